// Round 13
// baseline (529.405 us; speedup 1.0000x reference)
//
#include <hip/hip_runtime.h>
#include <hip/hip_bf16.h>

using bf16 = __hip_bfloat16;
typedef unsigned char u8;
typedef short bf16x8 __attribute__((ext_vector_type(8)));
typedef short bf16x4 __attribute__((ext_vector_type(4)));
typedef float f32x4 __attribute__((ext_vector_type(4)));

#define BNS 0.9999950000374997f   // folded into weights at prep time
#define MFMA_B16 __builtin_amdgcn_mfma_f32_16x16x32_bf16

__device__ __forceinline__ short f2bs(float v){ bf16 h = __float2bfloat16(v); return *reinterpret_cast<short*>(&h); }
__device__ __forceinline__ float s2f(short s){ union{unsigned u; float f;} x; x.u = ((unsigned)(unsigned short)s) << 16; return x.f; }
__device__ __forceinline__ float lrelu(float a){ return fmaxf(a, 0.2f*a); }
__device__ __forceinline__ bf16x8 ld8(const short* p){ return *(const bf16x8*)(p); }

// ---------------- fused prep: masks (independent via pool composition) + weights ----
__global__ __launch_bounds__(256) void k_prep(const float* __restrict__ roi,
                                              const float* __restrict__ w1b,
                                              const float* __restrict__ i2,
                                              const float* __restrict__ l5,
                                              const float* __restrict__ r1a,
                                              const float* __restrict__ w2b,
                                              const float* __restrict__ w2a,
                                              const float* __restrict__ inv4,
                                              const float* __restrict__ w4b,
                                              const float* __restrict__ l4s,
                                              const float* __restrict__ r4w1,
                                              const float* __restrict__ w4a,
                                              const float* __restrict__ w1a,
                                              const float* __restrict__ r1w2,
                                              const float* __restrict__ r4w2,
                                              u8* __restrict__ M1, u8* __restrict__ M2, u8* __restrict__ M4,
                                              short* __restrict__ WT, short* __restrict__ WT4,
                                              short* __restrict__ d1a, short* __restrict__ dh)
{
    const int HW1 = 384*384, HW2 = 192*192, HW4 = 96*96;
    int bid = blockIdx.x, tid = threadIdx.x;
    if (bid < 4608){
        int i = bid*256 + tid;
        M1[i] = (roi[i] > 0.8f) ? 1 : 0;
    } else if (bid < 5760){
        int i = (bid-4608)*256 + tid;
        int n = i / HW2, p = i - n*HW2;
        int oy = p / 192, ox = p - oy*192;
        const float* r = roi + (size_t)n*HW1;
        int v = 0;
        #pragma unroll
        for (int ky=0; ky<3; ky++){
            int iy = 2*oy + ky - 1;
            if ((unsigned)iy >= 384u) continue;
            #pragma unroll
            for (int kx=0; kx<3; kx++){
                int ix = 2*ox + kx - 1;
                if ((unsigned)ix < 384u) v |= (r[iy*384 + ix] > 0.8f);
            }
        }
        M2[i] = (u8)v;
    } else if (bid < 6048){
        int i = (bid-5760)*256 + tid;
        int n = i / HW4, p = i - n*HW4;
        int oy = p / 96, ox = p - oy*96;
        const float* r = roi + (size_t)n*HW1;
        int v = 0;
        for (int dy=-3; dy<=3; dy++){
            int iy = 4*oy + dy;
            if ((unsigned)iy >= 384u) continue;
            for (int dx=-3; dx<=3; dx++){
                int ix = 4*ox + dx;
                if ((unsigned)ix < 384u) v |= (r[iy*384 + ix] > 0.8f);
            }
        }
        M4[i] = (u8)v;
    } else if (bid < 6264){
        int local = bid - 6048;
        int a = local / 36;
        int j = (local - a*36)*256 + tid;
        const float* src = (a==0)? w1b : (a==1)? i2 : (a==2)? l5 : (a==3)? r1a : (a==4)? w2b : w2a;
        float sc = (a==2) ? 1.0f : BNS;
        if (j < 9216){
            int co = j/288, r = j%288, ci = r/9, k = r%9;
            WT[a*9216 + k*1024 + co*32 + ci] = f2bs(src[j]*sc);
        }
    } else if (bid < 6984){
        int local = bid - 6264;
        int a = local / 144;
        int j = (local - a*144)*256 + tid;
        if (a < 2){
            if (j < 36864){
                int co = j/576, r = j%576, ci = r/9, k = r%9;
                const float* s = a ? w4b : inv4;
                WT4[a*36864 + k*4096 + co*64 + ci] = f2bs(s[j]*BNS);
            }
        } else if (a < 4){
            if (j < 18432){
                int co = j/576, r = j%576, ci = r/9, k = r%9;
                const float* s = (a==2) ? l4s : r4w1;
                float sc = (a==2) ? 1.0f : BNS;
                WT4[73728 + (a-2)*18432 + k*2048 + co*64 + ci] = f2bs(s[j]*sc);
            }
        } else {
            if (j < 18432){
                int co = j/288, r = j%288, ci = r/9, k = r%9;
                WT4[110592 + k*2048 + co*32 + ci] = f2bs(w4a[j]*BNS);
            }
        }
    } else {
        int local = bid - 6984;
        int a = local / 18;
        int j = (local - a*18)*256 + tid;
        if (a == 0){
            if (j < 2048){
                int h = j >> 10, r = j & 1023, co = r >> 5, kq = r & 31;
                int q = h*32 + kq;
                d1a[j] = (q < 36) ? f2bs(w1a[co*36 + q]*BNS) : 0;
            }
        } else {
            if (j < 4608){
                int k = j/512, r = j%512, co = r/32, ci = r%32;
                const float* s = (a==1) ? r1w2 : r4w2;
                dh[(a-1)*4608 + j] = (co == 0) ? f2bs(s[ci*9 + k]) : 0;
            }
        }
    }
}

// ---------------- generic MFMA stride-1 conv; k-outer / site-inner ------------
template<int CIN, int COUT, int EPI, int TH>
__global__ __launch_bounds__(256) void mconv_s1(const short* __restrict__ in, int H,
                                                const short* __restrict__ wT,
                                                const u8* __restrict__ mask,
                                                const float* __restrict__ res32,
                                                short* __restrict__ out, int tilesX)
{
    const int HW = H*H;
    const int HV = CIN/32, G = COUT/16, CH8 = CIN/8;
    const int SR = TH + 2;
    const int SITES = SR*18;
    const int PS = (SITES | 1)*8;
    const int U2N = TH/4;
    int tY = blockIdx.x / tilesX, tX = blockIdx.x % tilesX, n = blockIdx.z;
    int y0 = tY*TH, x0 = tX*16;

    __shared__ __align__(16) short s_in[CH8*((SITES|1)*8)];
    __shared__ u8 s_m[TH*16];

    int tid = threadIdx.x;
    const short* inN = in + (size_t)n*HW*CIN;
    for (int i = tid; i < SITES*CH8; i += 256){
        int r = i/CH8, q = i%CH8;     // CH8 pow2 -> shifts
        int ry = r/18, rx = r%18;
        int gy = y0-1+ry, gx = x0-1+rx;
        bf16x8 v = {0,0,0,0,0,0,0,0};
        if ((unsigned)gy < (unsigned)H && (unsigned)gx < (unsigned)H)
            v = *(const bf16x8*)(inN + ((size_t)gy*H + gx)*CIN + q*8);
        *(bf16x8*)(s_in + q*PS + r*8) = v;
    }
    for (int i = tid; i < TH*16; i += 256){
        int ty = i>>4, tx = i&15;
        s_m[i] = mask[(size_t)n*HW + (y0+ty)*H + x0+tx];
    }
    __syncthreads();

    int wv = tid >> 6, lane = tid & 63;
    int nQ = lane >> 4, nn = lane & 15;

    f32x4 acc[U2N][G];
    #pragma unroll
    for (int u2=0; u2<U2N; ++u2)
        #pragma unroll
        for (int g=0; g<G; ++g) acc[u2][g] = (f32x4){0,0,0,0};

    #pragma unroll
    for (int h=0; h<HV; ++h){
        const short* bh[U2N];
        #pragma unroll
        for (int u2=0; u2<U2N; ++u2){
            int ty = u2*4 + wv;
            bh[u2] = s_in + (h*4+nQ)*PS + (ty*18 + nn)*8;
        }
        #pragma unroll
        for (int ky=0; ky<3; ++ky)
            #pragma unroll
            for (int kx=0; kx<3; ++kx){
                const int k = ky*3+kx;
                bf16x8 a[G];
                #pragma unroll
                for (int g=0; g<G; ++g)
                    a[g] = *(const bf16x8*)(wT + k*COUT*CIN + (g*16+nn)*CIN + h*32 + nQ*8);
                #pragma unroll
                for (int u2=0; u2<U2N; ++u2){
                    bf16x8 bfr = ld8(bh[u2] + (ky*18+kx)*8);
                    #pragma unroll
                    for (int g=0; g<G; ++g)
                        acc[u2][g] = MFMA_B16(a[g], bfr, acc[u2][g], 0,0,0);
                }
            }
    }

    #pragma unroll
    for (int u2=0; u2<U2N; ++u2){
        int nt = u2*4 + wv;
        int p = (y0+nt)*H + x0+nn;
        u8 m = s_m[nt*16 + nn];
        short* op = out + ((size_t)n*HW + p)*COUT;
        #pragma unroll
        for (int g=0; g<G; ++g){
            float r[4];
            #pragma unroll
            for (int e=0; e<4; ++e){
                int co = g*16 + nQ*4 + e;
                float a = acc[u2][g][e], o;
                if      (EPI == 0) o = m ? fmaxf(a,0.f) : 0.f;
                else if (EPI == 1) o = m ? lrelu(a) : 0.f;
                else o = m ? fmaxf(a,0.f) + res32[((size_t)(n>>2)*COUT + co)*(size_t)HW + p] : 0.f;
                r[e] = o;
            }
            bf16x4 w4 = {f2bs(r[0]),f2bs(r[1]),f2bs(r[2]),f2bs(r[3])};
            *(bf16x4*)(op + g*16 + nQ*4) = w4;
        }
    }
}

// ---------------- MFMA stride-2 conv: CIN=32; k-outer / site-inner ----------
template<int COUT, int THO>
__global__ __launch_bounds__(256) void mconv_s2m(const short* __restrict__ in, int IH,
                                                 const short* __restrict__ wT,   // [9][COUT][32]
                                                 const u8* __restrict__ mask,
                                                 short* __restrict__ out, int OH, int tilesX)
{
    const int IHW = IH*IH, OHW = OH*OH, G = COUT/16;
    const int IR = 2*THO + 1;
    const int SITES = IR*33;
    const int PS = (SITES|1)*8;
    const int ITN = THO/4;
    int tY = blockIdx.x / tilesX, tX = blockIdx.x % tilesX, n = blockIdx.z;
    int y0 = tY*THO, x0 = tX*16;

    __shared__ __align__(16) short s_in[4*((SITES|1)*8)];
    __shared__ u8 s_m[THO*16];

    int tid = threadIdx.x;
    const short* inN = in + (size_t)n*IHW*32;
    for (int i = tid; i < SITES*4; i += 256){
        int r = i>>2, q = i&3;
        int ry = r/33, rx = r%33;
        int gy = 2*y0-1+ry, gx = 2*x0-1+rx;
        bf16x8 v = {0,0,0,0,0,0,0,0};
        if ((unsigned)gy < (unsigned)IH && (unsigned)gx < (unsigned)IH)
            v = *(const bf16x8*)(inN + ((size_t)gy*IH + gx)*32 + q*8);
        *(bf16x8*)(s_in + q*PS + r*8) = v;
    }
    for (int i = tid; i < THO*16; i += 256){
        int ty = i>>4, tx = i&15;
        s_m[i] = mask[(size_t)n*OHW + (y0+ty)*OH + x0+tx];
    }
    __syncthreads();

    int wv = tid >> 6, lane = tid & 63;
    int nQ = lane >> 4, nn = lane & 15;

    f32x4 acc[ITN][G];
    #pragma unroll
    for (int it=0; it<ITN; ++it)
        #pragma unroll
        for (int g=0; g<G; ++g) acc[it][g] = (f32x4){0,0,0,0};

    const short* pb[ITN];
    #pragma unroll
    for (int it=0; it<ITN; ++it){
        int nt = it*4 + wv;
        pb[it] = s_in + nQ*PS + ((2*nt)*33 + 2*nn)*8;
    }

    #pragma unroll
    for (int ky=0; ky<3; ++ky)
        #pragma unroll
        for (int kx=0; kx<3; ++kx){
            const int k = ky*3+kx;
            bf16x8 a[G];
            #pragma unroll
            for (int g=0; g<G; ++g)
                a[g] = *(const bf16x8*)(wT + k*COUT*32 + (g*16+nn)*32 + nQ*8);
            #pragma unroll
            for (int it=0; it<ITN; ++it){
                bf16x8 bfr = ld8(pb[it] + (ky*33+kx)*8);
                #pragma unroll
                for (int g=0; g<G; ++g)
                    acc[it][g] = MFMA_B16(a[g], bfr, acc[it][g], 0,0,0);
            }
        }

    #pragma unroll
    for (int it=0; it<ITN; ++it){
        int nt = it*4 + wv;
        int p = (y0+nt)*OH + x0+nn;
        u8 m = s_m[nt*16 + nn];
        short* op = out + ((size_t)n*OHW + p)*COUT;
        #pragma unroll
        for (int g=0; g<G; ++g){
            float r[4];
            #pragma unroll
            for (int e=0; e<4; ++e) r[e] = m ? fmaxf(acc[it][g][e],0.f) : 0.f;
            bf16x4 w4 = {f2bs(r[0]),f2bs(r[1]),f2bs(r[2]),f2bs(r[3])};
            *(bf16x4*)(op + g*16 + nQ*4) = w4;
        }
    }
}

// ---------------- fused refine_OS4: t = lrelu(conv64->32(xs))*m4; out = conv32->1(t)+b ----
template<int TH>
__global__ __launch_bounds__(256) void mconv_ref4(const short* __restrict__ in, int H,
                                                  const short* __restrict__ wTa,   // [9][32co][64ci]
                                                  const short* __restrict__ wTh,   // [9][16][32]
                                                  const float* __restrict__ bias,
                                                  const u8* __restrict__ mask,
                                                  float* __restrict__ out, int tilesX)
{
    const int HW = H*H;
    const int XR = TH+4, XSITES = XR*20;
    const int PSX = (XSITES|1)*8;
    const int TR = TH+2, TSITES = TR*18;
    const int PST = (TSITES|1)*8;
    int tY = blockIdx.x / tilesX, tX = blockIdx.x % tilesX, n = blockIdx.z;
    int y0 = tY*TH, x0 = tX*16;

    __shared__ __align__(16) short s_xs[8*((XSITES|1)*8)];
    __shared__ __align__(16) short s_t[4*((TSITES|1)*8)];
    __shared__ u8 s_m[TSITES];

    int tid = threadIdx.x;
    const short* inN = in + (size_t)n*HW*64;
    for (int i = tid; i < XSITES*8; i += 256){
        int r = i>>3, q = i&7;
        int ry = r/20, rx = r%20;
        int gy = y0-2+ry, gx = x0-2+rx;
        bf16x8 v = {0,0,0,0,0,0,0,0};
        if ((unsigned)gy < (unsigned)H && (unsigned)gx < (unsigned)H)
            v = *(const bf16x8*)(inN + ((size_t)gy*H + gx)*64 + q*8);
        *(bf16x8*)(s_xs + q*PSX + r*8) = v;
    }
    for (int i = tid; i < TSITES; i += 256){
        int vy = i/18, vx = i%18;
        int gy = y0-1+vy, gx = x0-1+vx;
        s_m[i] = ((unsigned)gy < (unsigned)H && (unsigned)gx < (unsigned)H) ? mask[(size_t)n*HW + gy*H + gx] : 0;
    }
    __syncthreads();

    int wv = tid >> 6, lane = tid & 63;
    int nQ = lane >> 4, nn = lane & 15;

    // t-phase (dense; mask4 is near-full density)
    const int TG = (TSITES + 15)/16;
    for (int g8 = wv; g8 < TG; g8 += 4){
        int s0 = g8*16 + nn;
        int s = s0 >= TSITES ? TSITES-1 : s0;
        int vy = s/18, vx = s - vy*18;
        const short* pb = s_xs + nQ*PSX + (vy*20 + vx)*8;
        f32x4 acc0 = {0,0,0,0}, acc1 = {0,0,0,0};
        #pragma unroll
        for (int ky=0; ky<3; ++ky)
            #pragma unroll
            for (int kx=0; kx<3; ++kx){
                const int k = ky*3+kx;
                const short* wk = wTa + k*2048;
                bf16x8 xlo = ld8(pb + (ky*20+kx)*8);
                bf16x8 xhi = ld8(pb + 4*PSX + (ky*20+kx)*8);
                bf16x8 a0lo = *(const bf16x8*)(wk + nn*64 + nQ*8);
                bf16x8 a0hi = *(const bf16x8*)(wk + nn*64 + 32 + nQ*8);
                bf16x8 a1lo = *(const bf16x8*)(wk + (16+nn)*64 + nQ*8);
                bf16x8 a1hi = *(const bf16x8*)(wk + (16+nn)*64 + 32 + nQ*8);
                acc0 = MFMA_B16(a0lo, xlo, acc0, 0,0,0);
                acc0 = MFMA_B16(a0hi, xhi, acc0, 0,0,0);
                acc1 = MFMA_B16(a1lo, xlo, acc1, 0,0,0);
                acc1 = MFMA_B16(a1hi, xhi, acc1, 0,0,0);
            }
        if (s0 < TSITES){
            u8 m = s_m[s0];
            #pragma unroll
            for (int g=0; g<2; ++g){
                float r[4];
                #pragma unroll
                for (int e=0; e<4; ++e){
                    float a = g ? acc1[e] : acc0[e];
                    r[e] = m ? lrelu(a) : 0.f;
                }
                bf16x4 w4 = {f2bs(r[0]),f2bs(r[1]),f2bs(r[2]),f2bs(r[3])};
                *(bf16x4*)(s_t + (g*2 + (nQ>>1))*PST + s0*8 + (nQ&1)*4) = w4;
            }
        }
    }
    __syncthreads();

    // head
    float bb = bias[0];
    for (int nt = wv; nt < TH; nt += 4){
        const short* pt = s_t + nQ*PST + (nt*18 + nn)*8;
        f32x4 acc = {0,0,0,0};
        #pragma unroll
        for (int ky=0; ky<3; ++ky)
            #pragma unroll
            for (int kx=0; kx<3; ++kx){
                const int k = ky*3+kx;
                bf16x8 aw = *(const bf16x8*)(wTh + k*512 + nn*32 + nQ*8);
                bf16x8 bfr = ld8(pt + (ky*18+kx)*8);
                acc = MFMA_B16(aw, bfr, acc, 0,0,0);
            }
        if (nQ == 0){
            u8 m = s_m[(nt+1)*18 + nn+1];
            out[(size_t)n*HW + (size_t)(y0+nt)*H + (x0+nn)] = m ? acc[0] + bb : -99.f;
        }
    }
}

// ---------------- conv1ab v7: sparse compacted site lists (mask1 ~20% dense) ----
__global__ __launch_bounds__(256) void conv1ab3(const float* __restrict__ image,
                                                const float* __restrict__ masks,
                                                const u8*  __restrict__ M1,
                                                const short* __restrict__ wT1a,   // [2][32co][32K]
                                                const short* __restrict__ wT1b,   // [9][32co][32ci]
                                                short* __restrict__ fea1)         // [N][HW][32]
{
    const int H = 384; const int HW = H*H;
    const int PS = 181*8;
    int tY = blockIdx.x / 48, tX = blockIdx.x % 48, n = blockIdx.z;
    int y0 = tY*16, x0 = tX*8;

    __shared__ float s_inp[4][240];
    __shared__ u8    s_m[240];
    __shared__ int   s_cnt[2];
    __shared__ unsigned short s_lF[180];
    __shared__ unsigned short s_lO[128];
    __shared__ __align__(16) short s_ic[8*(181*8)];
    __shared__ __align__(16) short s_f[4*(181*8)];

    int tid = threadIdx.x;
    const bf16x8 Z8 = {0,0,0,0,0,0,0,0};
    if (tid < 2) s_cnt[tid] = 0;
    // zero s_f (separate buffer -> no overlay hazard)
    for (int i = tid; i < 4*181; i += 256)
        *(bf16x8*)(s_f + i*8) = Z8;
    for (int i = tid; i < 240; i += 256){
        int ly = i/12, lxx = i%12;
        int gy = y0-2+ly, gx = x0-2+lxx;
        bool inb = ((unsigned)gy < 384u) && ((unsigned)gx < 384u);
        u8 mv = inb ? M1[(size_t)n*HW + gy*H + gx] : 0;
        s_m[i] = mv;
        float mm = (float)mv;
        int p = gy*H + gx;
        #pragma unroll
        for (int c = 0; c < 4; ++c){
            float v = 0.f;
            if (inb) v = (c < 3) ? image[((size_t)(n>>2)*3 + c)*HW + p]
                                 : masks[(size_t)n*HW + p];
            s_inp[c][i] = v*mm;
        }
    }
    __syncthreads();

    // build active-site lists
    for (int i = tid; i < 180; i += 256){
        int fy = i/10, fx = i - fy*10;
        if (s_m[(fy+1)*12 + fx+1]){
            int idx = atomicAdd(&s_cnt[0], 1);
            s_lF[idx] = (unsigned short)i;
        }
    }
    for (int i = tid; i < 128; i += 256){
        int ty = i>>3, tx = i&7;
        if (s_m[(ty+2)*12 + tx+2]){
            int idx = atomicAdd(&s_cnt[1], 1);
            s_lO[idx] = (unsigned short)i;
        }
    }
    __syncthreads();

    int cntF = s_cnt[0], cntO = s_cnt[1];

    // im2col only at listed f-sites (q fixed per thread since 256 % 64 == 0)
    {
        int q = tid & 63;
        int ci = q/9, kk = q - ci*9, ky = kk/3, kx = kk - ky*3;
        bool qok = q < 36;
        for (int i = tid; i < cntF*64; i += 256){
            int site = s_lF[i >> 6];
            short v = 0;
            if (qok){
                int fy = site/10, fx = site - fy*10;
                v = f2bs(s_inp[ci][(fy+ky)*12 + fx+kx]);
            }
            s_ic[(q>>3)*PS + site*8 + (q&7)] = v;
        }
    }
    __syncthreads();

    int wv = tid >> 6, lane = tid & 63;
    int nQ = lane >> 4, nn = lane & 15;

    // f-stage over listed groups; write straight to s_f (zeros elsewhere)
    {
        bf16x8 fa0[2], fa1[2];
        #pragma unroll
        for (int h=0;h<2;++h){
            fa0[h] = *(const bf16x8*)(wT1a + h*1024 + nn*32 + nQ*8);
            fa1[h] = *(const bf16x8*)(wT1a + h*1024 + (16+nn)*32 + nQ*8);
        }
        for (int base = wv*16; base < cntF; base += 64){
            int slot = base + nn;
            bool on = slot < cntF;
            int site = s_lF[on ? slot : 0];
            f32x4 a0 = {0,0,0,0}, a1 = {0,0,0,0};
            #pragma unroll
            for (int h=0;h<2;++h){
                bf16x8 bfr = ld8(s_ic + (h*4+nQ)*PS + site*8);
                a0 = MFMA_B16(fa0[h], bfr, a0, 0,0,0);
                a1 = MFMA_B16(fa1[h], bfr, a1, 0,0,0);
            }
            if (on){
                #pragma unroll
                for (int g=0; g<2; ++g){
                    float r[4];
                    #pragma unroll
                    for (int e=0; e<4; ++e){
                        float a = g ? a1[e] : a0[e];
                        r[e] = fmaxf(a,0.f);
                    }
                    bf16x4 w4 = {f2bs(r[0]),f2bs(r[1]),f2bs(r[2]),f2bs(r[3])};
                    *(bf16x4*)(s_f + (g*2 + (nQ>>1))*PS + site*8 + (nQ&1)*4) = w4;
                }
            }
        }
    }
    __syncthreads();

    // conv1b over listed output groups (k-loop per group, weights from L1)
    {
        for (int base = wv*16; base < cntO; base += 64){
            int slot = base + nn;
            bool on = slot < cntO;
            int os = s_lO[on ? slot : 0];
            int ty = os >> 3, tx = os & 7;
            const short* pb = s_f + nQ*PS + (ty*10 + tx)*8;
            f32x4 acc0 = {0,0,0,0}, acc1 = {0,0,0,0};
            #pragma unroll
            for (int ky=0; ky<3; ++ky)
                #pragma unroll
                for (int kx=0; kx<3; ++kx){
                    const int k = ky*3+kx;
                    bf16x8 a0 = *(const bf16x8*)(wT1b + k*1024 + nn*32 + nQ*8);
                    bf16x8 a1 = *(const bf16x8*)(wT1b + k*1024 + (16+nn)*32 + nQ*8);
                    bf16x8 bfr = ld8(pb + (ky*10+kx)*8);
                    acc0 = MFMA_B16(a0, bfr, acc0, 0,0,0);
                    acc1 = MFMA_B16(a1, bfr, acc1, 0,0,0);
                }
            if (on){
                short* fp = fea1 + ((size_t)n*HW + (size_t)(y0+ty)*H + (x0+tx))*32;
                #pragma unroll
                for (int g=0; g<2; ++g){
                    float r[4];
                    #pragma unroll
                    for (int e=0; e<4; ++e){
                        float a = g ? acc1[e] : acc0[e];
                        r[e] = fmaxf(a,0.f);
                    }
                    bf16x4 w4 = {f2bs(r[0]),f2bs(r[1]),f2bs(r[2]),f2bs(r[3])};
                    *(bf16x4*)(fp + g*16 + nQ*4) = w4;
                }
            }
        }
        // zero inactive fea1 sites (needed by dense downstream consumers)
        for (int i = tid; i < 128*4; i += 256){
            int os = i >> 2, q = i & 3;
            int ty = os >> 3, tx = os & 7;
            if (!s_m[(ty+2)*12 + tx+2])
                *(bf16x8*)(fea1 + ((size_t)n*HW + (size_t)(y0+ty)*H + (x0+tx))*32 + q*8) = Z8;
        }
    }
}

// ---------------- MFMA layer4 v2: 16x8 tile -> 31KB LDS, 5 blocks/CU ----------------
__global__ __launch_bounds__(256) void fk_l4c(const short* __restrict__ xs,
                                              const short* __restrict__ fea2,
                                              const u8*  __restrict__ M2,
                                              const short* __restrict__ wTi4,
                                              const short* __restrict__ wTl4,
                                              short* __restrict__ u_out)
{
    const int H2 = 192, HW2 = H2*H2, H4 = 96, HW4 = H4*H4;
    const int PSX = 61*8, PSU = 181*8;
    int tY = blockIdx.x / 24, tX = blockIdx.x % 24, n = blockIdx.z;
    int y0 = tY*16, x0 = tX*8;
    int uy0 = (y0>>1) - 1, ux0 = (x0>>1) - 1;

    __shared__ __align__(16) short s_xs[8*(61*8)];   // 60 sites (10x6), 64 ch
    __shared__ __align__(16) short s_ul[8*(181*8)];  // 180 sites (18x10), 64 ch
    __shared__ u8 s_m[180];

    int tid = threadIdx.x;
    const short* xN = xs + (size_t)n*HW4*64;
    for (int i = tid; i < 60*8; i += 256){
        int r = i>>3, q = i&7;
        int ly = r/6, lxx = r%6;
        int gy = uy0+ly, gx = ux0+lxx;
        bf16x8 v = {0,0,0,0,0,0,0,0};
        if ((unsigned)gy < 96u && (unsigned)gx < 96u)
            v = *(const bf16x8*)(xN + ((size_t)gy*H4 + gx)*64 + q*8);
        *(bf16x8*)(s_xs + q*PSX + r*8) = v;
    }
    for (int i = tid; i < 180; i += 256){
        int ry = i/10, rx = i%10; int gy = y0-1+ry, gx = x0-1+rx;
        s_m[i] = ((unsigned)gy < 192u && (unsigned)gx < 192u) ? M2[(size_t)n*HW2 + gy*H2 + gx] : 0;
    }

    int wv = tid >> 6, lane = tid & 63;
    int nQ = lane >> 4, nn = lane & 15;

    bf16x4 pf2v[2][2];
    {
        const short* f2N = fea2 + (size_t)n*HW2*32;
        #pragma unroll
        for (int u2=0; u2<2; ++u2){
            int s0 = (u2*4 + wv)*16 + nn;
            int ty = s0 >> 3, tx = s0 & 7;
            int p = (y0+ty)*H2 + x0+tx;
            const short* fp = f2N + (size_t)p*32;
            pf2v[u2][0] = *(const bf16x4*)(fp + nQ*4);
            pf2v[u2][1] = *(const bf16x4*)(fp + 16 + nQ*4);
        }
    }
    __syncthreads();

    // stage 1: inverse-conv to 180 ul sites; 4 parity classes of 45 (3 groups each)
    for (int ui = wv; ui < 12; ui += 4){
        int cls = ui/3, nt = ui%3;
        int pY = cls >> 1, pX = cls & 1;
        int s0 = nt*16 + nn;
        int s = s0 > 44 ? 44 : s0;
        int jr = s/5, jc = s%5;
        int ry = 2*jr + pY, rx = 2*jc + pX;

        int tiy[4], tix[4], twk[4]; int tapN;
        if (pY == 0){
            if (pX == 0){
                tiy[0]=jr;   tix[0]=jc;   twk[0]=8;
                tiy[1]=jr;   tix[1]=jc+1; twk[1]=6;
                tiy[2]=jr+1; tix[2]=jc;   twk[2]=2;
                tiy[3]=jr+1; tix[3]=jc+1; twk[3]=0; tapN=4;
            } else {
                tiy[0]=jr;   tix[0]=jc+1; twk[0]=7;
                tiy[1]=jr+1; tix[1]=jc+1; twk[1]=1; tapN=2;
            }
        } else {
            if (pX == 0){
                tiy[0]=jr+1; tix[0]=jc;   twk[0]=5;
                tiy[1]=jr+1; tix[1]=jc+1; twk[1]=3; tapN=2;
            } else {
                tiy[0]=jr+1; tix[0]=jc+1; twk[0]=4; tapN=1;
            }
        }

        f32x4 acc[4];
        #pragma unroll
        for (int g=0; g<4; ++g) acc[g] = (f32x4){0,0,0,0};
        for (int t = 0; t < tapN; ++t){
            int off = (tiy[t]*6 + tix[t])*8;
            bf16x8 xlo = ld8(s_xs + nQ*PSX + off);
            bf16x8 xhi = ld8(s_xs + (4+nQ)*PSX + off);
            const short* wk = wTi4 + twk[t]*4096;
            #pragma unroll
            for (int g=0; g<4; ++g){
                bf16x8 alo = *(const bf16x8*)(wk + (g*16+nn)*64 + nQ*8);
                bf16x8 ahi = *(const bf16x8*)(wk + (g*16+nn)*64 + 32 + nQ*8);
                acc[g] = MFMA_B16(alo, xlo, acc[g], 0,0,0);
                acc[g] = MFMA_B16(ahi, xhi, acc[g], 0,0,0);
            }
        }
        if (s0 <= 44){
            int sidx = ry*10 + rx;
            u8 m = s_m[sidx];
            #pragma unroll
            for (int g=0; g<4; ++g){
                float r[4];
                #pragma unroll
                for (int e=0; e<4; ++e){
                    float a = acc[g][e];
                    r[e] = m ? lrelu(a) : 0.f;
                }
                bf16x4 w4 = {f2bs(r[0]),f2bs(r[1]),f2bs(r[2]),f2bs(r[3])};
                *(bf16x4*)(s_ul + ((g>>1)*4 + (g&1)*2 + (nQ>>1))*PSU + sidx*8 + (nQ&1)*4) = w4;
            }
        }
    }
    __syncthreads();

    // stage 2: conv64->32 over 128 outputs (2 groups/wave, 2 rows x 8 cols per group)
    {
        f32x4 acc0[2], acc1[2];
        const short* pv[2];
        #pragma unroll
        for (int u2=0; u2<2; ++u2){
            acc0[u2] = (f32x4){0,0,0,0}; acc1[u2] = (f32x4){0,0,0,0};
            int s0 = (u2*4 + wv)*16 + nn;
            int ty = s0 >> 3, tx = s0 & 7;
            pv[u2] = s_ul + nQ*PSU + (ty*10 + tx)*8;
        }
        #pragma unroll
        for (int ky=0; ky<3; ++ky)
            #pragma unroll
            for (int kx=0; kx<3; ++kx){
                int k = ky*3+kx;
                const short* wk = wTl4 + k*2048;
                bf16x8 a0lo = *(const bf16x8*)(wk + nn*64 + nQ*8);
                bf16x8 a0hi = *(const bf16x8*)(wk + nn*64 + 32 + nQ*8);
                bf16x8 a1lo = *(const bf16x8*)(wk + (16+nn)*64 + nQ*8);
                bf16x8 a1hi = *(const bf16x8*)(wk + (16+nn)*64 + 32 + nQ*8);
                #pragma unroll
                for (int u2=0; u2<2; ++u2){
                    bf16x8 vlo = ld8(pv[u2] + (ky*10+kx)*8);
                    bf16x8 vhi = ld8(pv[u2] + 4*PSU + (ky*10+kx)*8);
                    acc0[u2] = MFMA_B16(a0lo, vlo, acc0[u2], 0,0,0);
                    acc0[u2] = MFMA_B16(a0hi, vhi, acc0[u2], 0,0,0);
                    acc1[u2] = MFMA_B16(a1lo, vlo, acc1[u2], 0,0,0);
                    acc1[u2] = MFMA_B16(a1hi, vhi, acc1[u2], 0,0,0);
                }
            }
        #pragma unroll
        for (int u2 = 0; u2 < 2; ++u2){
            int s0 = (u2*4 + wv)*16 + nn;
            int ty = s0 >> 3, tx = s0 & 7;
            int p = (y0+ty)*H2 + x0+tx;
            u8 m = s_m[(ty+1)*10 + tx+1];
            short* up = u_out + ((size_t)n*HW2 + p)*32;
            #pragma unroll
            for (int g=0; g<2; ++g){
                float r[4];
                #pragma unroll
                for (int e=0; e<4; ++e){
                    float a = g ? acc1[u2][e] : acc0[u2][e];
                    r[e] = m ? a + s2f(pf2v[u2][g][e]) : 0.f;
                }
                bf16x4 w4 = {f2bs(r[0]),f2bs(r[1]),f2bs(r[2]),f2bs(r[3])};
                *(bf16x4*)(up + g*16 + nQ*4) = w4;
            }
        }
    }
}

// ---------------- MFMA back end v14: sparse lists + T14 fea1 prefetch ----------------
__global__ __launch_bounds__(256) void fk_back8(const short* __restrict__ u,
                                                const short* __restrict__ fea1,   // [N][HW1][32]
                                                const u8*  __restrict__ M1,
                                                const short* __restrict__ wTi2,
                                                const short* __restrict__ wTl5,
                                                const short* __restrict__ wTr1a,
                                                const short* __restrict__ wTr1b,  // [9][16][32]
                                                const float* __restrict__ r1_b2,
                                                float* __restrict__ out1)
{
    const int H1 = 384, HW1 = H1*H1, H2 = 192, HW2 = H2*H2;
    const int PS_U = 97*8, PS_A = 309*8, PS_B = 241*8, PS_C = 181*8;
    int tY = blockIdx.x / 48, tX = blockIdx.x % 48, n = blockIdx.z;
    int y0 = tY*16, x0 = tX*8;
    int uy0 = (y0>>1) - 2, ux0 = (x0>>1) - 2;

    __shared__ __align__(16) short sP0[4*(309*8)];   // s_vl, then s_t1
    __shared__ __align__(16) short sP1[4*(241*8)];   // s_u, then s_v
    __shared__ u8 s_m[308];
    __shared__ int s_cnt[7];                          // A0..A3, B, C, D
    __shared__ unsigned s_lA[4*80];
    __shared__ unsigned s_lB[240];
    __shared__ unsigned s_lC[180];
    __shared__ unsigned s_lD[128];
    short* s_u  = sP1;
    short* s_vl = sP0;
    short* s_v  = sP1;
    short* s_t1 = sP0;

    int tid = threadIdx.x;
    const bf16x8 Z8 = {0,0,0,0,0,0,0,0};

    // ---- prologue: stage u, masks; zero vl; init counters ----
    if (tid < 7) s_cnt[tid] = 0;
    const short* uN = u + (size_t)n*HW2*32;
    for (int i = tid; i < 96*4; i += 256){
        int r = i>>2, q = i&3;
        int ly = r >> 3, lxx = r & 7;
        int gy = uy0+ly, gx = ux0+lxx;
        bf16x8 v = Z8;
        if ((unsigned)gy < 192u && (unsigned)gx < 192u)
            v = *(const bf16x8*)(uN + ((size_t)gy*H2 + gx)*32 + q*8);
        *(bf16x8*)(s_u + q*PS_U + r*8) = v;
    }
    for (int i = tid; i < 308; i += 256){
        int ry = i/14, rx = i%14; int gy = y0-3+ry, gx = x0-3+rx;
        s_m[i] = ((unsigned)gy < 384u && (unsigned)gx < 384u) ? M1[(size_t)n*HW1 + gy*H1 + gx] : 0;
    }
    for (int i = tid; i < 4*309; i += 256)
        *(bf16x8*)(s_vl + i*8) = Z8;
    __syncthreads();

    // ---- build compacted active-site lists ----
    for (int i = tid; i < 308; i += 256){
        if (s_m[i]){
            int ry = i/14, rx = i - ry*14;
            int cls = ((ry&1)<<1) | (rx&1);
            int jr = ry>>1, jc = rx>>1;
            int idx = atomicAdd(&s_cnt[cls], 1);
            s_lA[cls*80 + idx] = ((unsigned)i<<16) | (unsigned)(jr*8+jc);
        }
    }
    for (int i = tid; i < 240; i += 256){
        int vy = i/12, vx = i - vy*12;
        if (s_m[(vy+1)*14 + vx+1]){
            int idx = atomicAdd(&s_cnt[4], 1);
            s_lB[idx] = ((unsigned)i<<16) | (unsigned)(vy*14+vx);
        }
    }
    for (int i = tid; i < 180; i += 256){
        int qy = i/10, qx = i - qy*10;
        if (s_m[(qy+2)*14 + qx+2]){
            int idx = atomicAdd(&s_cnt[5], 1);
            s_lC[idx] = ((unsigned)i<<16) | (unsigned)(qy*12+qx);
        }
    }
    for (int i = tid; i < 128; i += 256){
        int ty = i>>3, tx = i&7;
        if (s_m[(ty+3)*14 + tx+3]){
            int idx = atomicAdd(&s_cnt[6], 1);
            s_lD[idx] = ((unsigned)i<<16) | (unsigned)(ty*10+tx);
        } else {
            out1[(size_t)n*HW1 + (size_t)(y0+ty)*H1 + (x0+tx)] = -99.f;
        }
    }
    __syncthreads();

    int wv = tid >> 6, lane = tid & 63;
    int nQ = lane >> 4, nn = lane & 15;

    // ---- T14 prefetch: issue stage-B fea1 residual loads now ----
    int cntB = s_cnt[4];
    bf16x4 pfB[4][2];
    #pragma unroll
    for (int it=0; it<4; ++it){
        int slot = wv*16 + it*64 + nn;
        if (slot < cntB){
            unsigned e = s_lB[slot];
            int wr = e >> 16;
            int vy = wr/12, vx = wr - vy*12;
            const short* f1 = fea1 + ((size_t)n*HW1 + (size_t)(y0-2+vy)*H1 + (x0-2+vx))*32;
            pfB[it][0] = *(const bf16x4*)(f1 + nQ*4);
            pfB[it][1] = *(const bf16x4*)(f1 + 16 + nQ*4);
        }
    }

    // ---- stage A (inv2): wave wv handles parity class wv ----
    {
        const int tN_[4]   = {4,2,2,1};
        const int tOff[4][4] = {{0,1,8,9},{1,9,9,9},{8,9,9,9},{9,9,9,9}};
        const int tWk [4][4] = {{8,6,2,0},{7,1,1,1},{5,3,3,3},{4,4,4,4}};
        int cnt = s_cnt[wv];
        int tn = tN_[wv];
        for (int base = 0; base < cnt; base += 16){
            int slot = base + nn;
            bool on = slot < cnt;
            unsigned e = s_lA[wv*80 + (on ? slot : 0)];
            int rb = e & 0xffff;
            f32x4 acc0 = {0,0,0,0}, acc1 = {0,0,0,0};
            for (int t = 0; t < tn; ++t){
                bf16x8 bfr = ld8(s_u + nQ*PS_U + (rb + tOff[wv][t])*8);
                const short* wp = wTi2 + tWk[wv][t]*1024;
                bf16x8 a0 = *(const bf16x8*)(wp + nn*32 + nQ*8);
                bf16x8 a1 = *(const bf16x8*)(wp + (16+nn)*32 + nQ*8);
                acc0 = MFMA_B16(a0, bfr, acc0, 0,0,0);
                acc1 = MFMA_B16(a1, bfr, acc1, 0,0,0);
            }
            if (on){
                int sidx = e >> 16;
                float r[8];
                #pragma unroll
                for (int g=0; g<2; ++g)
                    #pragma unroll
                    for (int ee=0; ee<4; ++ee)
                        r[g*4+ee] = lrelu(g ? acc1[ee] : acc0[ee]);
                bf16x4 w0 = {f2bs(r[0]),f2bs(r[1]),f2bs(r[2]),f2bs(r[3])};
                bf16x4 w1 = {f2bs(r[4]),f2bs(r[5]),f2bs(r[6]),f2bs(r[7])};
                *(bf16x4*)(s_vl + (nQ>>1)*PS_A     + sidx*8 + (nQ&1)*4) = w0;
                *(bf16x4*)(s_vl + (2+(nQ>>1))*PS_A + sidx*8 + (nQ&1)*4) = w1;
            }
        }
    }
    __syncthreads();

    // ---- zero v (overlays u; u now dead) ----
    for (int i = tid; i < 4*241; i += 256)
        *(bf16x8*)(s_v + i*8) = Z8;
    __syncthreads();

    // ---- stage B (l5 + fea1 residual from prefetched regs), compacted ----
    {
        #pragma unroll
        for (int it=0; it<4; ++it){
            int base = wv*16 + it*64;
            if (base < cntB){
                int slot = base + nn;
                bool on = slot < cntB;
                unsigned e = s_lB[on ? slot : 0];
                int rb = e & 0xffff;
                int wr = e >> 16;
                const short* pv = s_vl + nQ*PS_A + rb*8;
                f32x4 acc0 = {0,0,0,0}, acc1 = {0,0,0,0};
                #pragma unroll
                for (int ky=0; ky<3; ++ky)
                    #pragma unroll
                    for (int kx=0; kx<3; ++kx){
                        const int k = ky*3+kx;
                        bf16x8 wb0 = *(const bf16x8*)(wTl5 + k*1024 + nn*32 + nQ*8);
                        bf16x8 wb1 = *(const bf16x8*)(wTl5 + k*1024 + (16+nn)*32 + nQ*8);
                        bf16x8 bfr = ld8(pv + (ky*14+kx)*8);
                        acc0 = MFMA_B16(wb0, bfr, acc0, 0,0,0);
                        acc1 = MFMA_B16(wb1, bfr, acc1, 0,0,0);
                    }
                if (on){
                    float r[8];
                    #pragma unroll
                    for (int ee=0; ee<4; ++ee){
                        r[ee]   = acc0[ee] + s2f(pfB[it][0][ee]);
                        r[4+ee] = acc1[ee] + s2f(pfB[it][1][ee]);
                    }
                    bf16x4 w0 = {f2bs(r[0]),f2bs(r[1]),f2bs(r[2]),f2bs(r[3])};
                    bf16x4 w1 = {f2bs(r[4]),f2bs(r[5]),f2bs(r[6]),f2bs(r[7])};
                    *(bf16x4*)(s_v + (nQ>>1)*PS_B     + wr*8 + (nQ&1)*4) = w0;
                    *(bf16x4*)(s_v + (2+(nQ>>1))*PS_B + wr*8 + (nQ&1)*4) = w1;
                }
            }
        }
    }
    __syncthreads();

    // ---- zero t1 (overlays vl; vl now dead) ----
    for (int i = tid; i < 4*181; i += 256)
        *(bf16x8*)(s_t1 + i*8) = Z8;
    __syncthreads();

    // ---- stage C (r1a), compacted ----
    {
        int cnt = s_cnt[5];
        for (int base = wv*16; base < cnt; base += 64){
            int slot = base + nn;
            bool on = slot < cnt;
            unsigned e = s_lC[on ? slot : 0];
            int rb = e & 0xffff;
            const short* pv = s_v + nQ*PS_B + rb*8;
            f32x4 acc0 = {0,0,0,0}, acc1 = {0,0,0,0};
            #pragma unroll
            for (int ky=0; ky<3; ++ky)
                #pragma unroll
                for (int kx=0; kx<3; ++kx){
                    const int k = ky*3+kx;
                    bf16x8 wc0 = *(const bf16x8*)(wTr1a + k*1024 + nn*32 + nQ*8);
                    bf16x8 wc1 = *(const bf16x8*)(wTr1a + k*1024 + (16+nn)*32 + nQ*8);
                    bf16x8 bfr = ld8(pv + (ky*12+kx)*8);
                    acc0 = MFMA_B16(wc0, bfr, acc0, 0,0,0);
                    acc1 = MFMA_B16(wc1, bfr, acc1, 0,0,0);
                }
            if (on){
                int wr = e >> 16;
                float r[8];
                #pragma unroll
                for (int g=0; g<2; ++g)
                    #pragma unroll
                    for (int ee=0; ee<4; ++ee)
                        r[g*4+ee] = lrelu(g ? acc1[ee] : acc0[ee]);
                bf16x4 w0 = {f2bs(r[0]),f2bs(r[1]),f2bs(r[2]),f2bs(r[3])};
                bf16x4 w1 = {f2bs(r[4]),f2bs(r[5]),f2bs(r[6]),f2bs(r[7])};
                *(bf16x4*)(s_t1 + (nQ>>1)*PS_C     + wr*8 + (nQ&1)*4) = w0;
                *(bf16x4*)(s_t1 + (2+(nQ>>1))*PS_C + wr*8 + (nQ&1)*4) = w1;
            }
        }
    }
    __syncthreads();

    // ---- stage D (r1b head), compacted; inactive already written -99 ----
    {
        float bb = r1_b2[0];
        int cnt = s_cnt[6];
        for (int base = wv*16; base < cnt; base += 64){
            int slot = base + nn;
            bool on = slot < cnt;
            unsigned e = s_lD[on ? slot : 0];
            int rb = e & 0xffff;
            const short* pt = s_t1 + nQ*PS_C + rb*8;
            f32x4 acc = {0,0,0,0};
            #pragma unroll
            for (int ky=0; ky<3; ++ky)
                #pragma unroll
                for (int kx=0; kx<3; ++kx){
                    const int k = ky*3+kx;
                    bf16x8 aw = *(const bf16x8*)(wTr1b + k*512 + nn*32 + nQ*8);
                    bf16x8 bfr = ld8(pt + (ky*10+kx)*8);
                    acc = MFMA_B16(aw, bfr, acc, 0,0,0);
                }
            if (on && nQ == 0){
                int wr = e >> 16;
                int ty = wr >> 3, tx = wr & 7;
                out1[(size_t)n*HW1 + (size_t)(y0+ty)*H1 + (x0+tx)] = acc[0] + bb;
            }
        }
    }
}

// ---------------- launch ----------------

extern "C" void kernel_launch(void* const* d_in, const int* in_sizes, int n_in,
                              void* d_out, int out_size, void* d_ws, size_t ws_size,
                              hipStream_t stream)
{
    const float* x      = (const float*)d_in[0];
    const float* image  = (const float*)d_in[1];
    const float* masks  = (const float*)d_in[2];
    const float* roi    = (const float*)d_in[3];
    const float* w1a    = (const float*)d_in[4];
    const float* w1b    = (const float*)d_in[5];
    const float* w2a    = (const float*)d_in[6];
    const float* w2b    = (const float*)d_in[7];
    const float* w4a    = (const float*)d_in[8];
    const float* w4b    = (const float*)d_in[9];
    const float* inv4_w = (const float*)d_in[10];
    const float* l4_sub = (const float*)d_in[11];
    const float* inv2_w = (const float*)d_in[12];
    const float* l5_sub = (const float*)d_in[13];
    const float* r4_w1  = (const float*)d_in[14];
    const float* r4_w2  = (const float*)d_in[15];
    const float* r4_b2  = (const float*)d_in[16];
    const float* r1_w1  = (const float*)d_in[17];
    const float* r1_w2  = (const float*)d_in[18];
    const float* r1_b2  = (const float*)d_in[19];
    float* out = (float*)d_out;

    const int N = 8;
    const int H1 = 384, HW1 = 384*384;
    const int H2 = 192, HW2 = 192*192;
    const int H4 = 96,  HW4 = 96*96;

    char* wsp = (char*)d_ws;
    size_t off = 0;
    auto alloc = [&](size_t bytes) -> char* {
        char* p = wsp + off;
        off += (bytes + 255) & ~(size_t)255;
        return p;
    };
    bf16* FEA1 = (bf16*)alloc((size_t)N*32*HW1*2);  // interleaved [N][HW1][32]
    u8*   M1   = (u8*)alloc((size_t)N*HW1);
    u8*   M2   = (u8*)alloc((size_t)N*HW2);
    u8*   M4   = (u8*)alloc((size_t)N*HW4);
    bf16* FEA2 = (bf16*)alloc((size_t)N*32*HW2*2);  // interleaved [N][HW2][32]
    bf16* XS   = (bf16*)alloc((size_t)N*64*HW4*2);  // interleaved [N][HW4][64]
    bf16* GU   = (bf16*)alloc((size_t)N*32*HW2*2);  // interleaved (g then u)
    bf16* HT   = (bf16*)alloc((size_t)N*64*HW4*2);  // interleaved (h 64ch)
    short* WT   = (short*)alloc(6*9216*2);
    short* WT4  = (short*)alloc((size_t)129024*2);
    short* WT1a = (short*)alloc(2048*2);
    short* WTh  = (short*)alloc(2*4608*2);
    (void)ws_size; (void)in_sizes; (void)n_in; (void)out_size;

    short* wT1b  = WT;
    short* wTi2  = WT + 9216;
    short* wTl5  = WT + 2*9216;
    short* wTr1a = WT + 3*9216;
    short* wT2b  = WT + 4*9216;
    short* wT2a  = WT + 5*9216;
    short* wTi4  = WT4;
    short* wT4b  = WT4 + 36864;
    short* wTl4  = WT4 + 73728;
    short* wTr4a = WT4 + 92160;
    short* wT4a  = WT4 + 110592;
    short* wTr1b = WTh;
    short* wTr4b = WTh + 4608;

    dim3 blk(256);

    // fused prep: all masks + all weight transforms in one dispatch
    k_prep<<<dim3(7038), blk, 0, stream>>>(roi, w1b, inv2_w, l5_sub, r1_w1, w2b, w2a,
                                           inv4_w, w4b, l4_sub, r4_w1, w4a,
                                           w1a, r1_w2, r4_w2,
                                           M1, M2, M4, WT, WT4, WT1a, WTh);

    // front
    conv1ab3<<<dim3(1152, 1, N), blk, 0, stream>>>(image, masks, M1, WT1a, wT1b, (short*)FEA1);
    mconv_s2m<32,8><<<dim3(288, 1, N), blk, 0, stream>>>((const short*)FEA1, H1, wT2a, M2, (short*)GU, H2, 12);
    mconv_s1<32,32,0,8><<<dim3(288, 1, N), blk, 0, stream>>>((const short*)GU, H2, wT2b, M2, nullptr, (short*)FEA2, 12);
    mconv_s2m<64,4><<<dim3(144, 1, N), blk, 0, stream>>>((const short*)FEA2, H2, wT4a, M4, (short*)HT, H4, 6);
    mconv_s1<64,64,3,4><<<dim3(144, 1, N), blk, 0, stream>>>((const short*)HT, H4, wT4b, M4, x, (short*)XS, 6);

    // refine_OS4 fused (t + head in one kernel)
    mconv_ref4<4><<<dim3(144, 1, N), blk, 0, stream>>>((const short*)XS, H4, wTr4a, wTr4b, r4_b2, M4, out, 6);

    // layer4 fused (MFMA) -> u  (16x8 tile, 5 blocks/CU)
    fk_l4c<<<dim3(288, 1, N), blk, 0, stream>>>((const short*)XS, (const short*)FEA2, M2,
                                                wTi4, wTl4, (short*)GU);

    // MFMA back end -> out1
    fk_back8<<<dim3(1152, 1, N), blk, 0, stream>>>((const short*)GU, (const short*)FEA1, M1,
                                                   wTi2, wTl5, wTr1a, wTr1b, r1_b2,
                                                   out + (size_t)N*HW4);
}

// Round 14
// 516.962 us; speedup vs baseline: 1.0241x; 1.0241x over previous
//
#include <hip/hip_runtime.h>
#include <hip/hip_bf16.h>

using bf16 = __hip_bfloat16;
typedef unsigned char u8;
typedef short bf16x8 __attribute__((ext_vector_type(8)));
typedef short bf16x4 __attribute__((ext_vector_type(4)));
typedef float f32x4 __attribute__((ext_vector_type(4)));

#define BNS 0.9999950000374997f   // folded into weights at prep time
#define MFMA_B16 __builtin_amdgcn_mfma_f32_16x16x32_bf16

__device__ __forceinline__ short f2bs(float v){ bf16 h = __float2bfloat16(v); return *reinterpret_cast<short*>(&h); }
__device__ __forceinline__ float s2f(short s){ union{unsigned u; float f;} x; x.u = ((unsigned)(unsigned short)s) << 16; return x.f; }
__device__ __forceinline__ float lrelu(float a){ return fmaxf(a, 0.2f*a); }
__device__ __forceinline__ bf16x8 ld8(const short* p){ return *(const bf16x8*)(p); }

// ---------------- fused prep: masks (independent via pool composition) + weights ----
__global__ __launch_bounds__(256) void k_prep(const float* __restrict__ roi,
                                              const float* __restrict__ w1b,
                                              const float* __restrict__ i2,
                                              const float* __restrict__ l5,
                                              const float* __restrict__ r1a,
                                              const float* __restrict__ w2b,
                                              const float* __restrict__ w2a,
                                              const float* __restrict__ inv4,
                                              const float* __restrict__ w4b,
                                              const float* __restrict__ l4s,
                                              const float* __restrict__ r4w1,
                                              const float* __restrict__ w4a,
                                              const float* __restrict__ w1a,
                                              const float* __restrict__ r1w2,
                                              const float* __restrict__ r4w2,
                                              u8* __restrict__ M1, u8* __restrict__ M2, u8* __restrict__ M4,
                                              short* __restrict__ WT, short* __restrict__ WT4,
                                              short* __restrict__ d1a, short* __restrict__ dh)
{
    const int HW1 = 384*384, HW2 = 192*192, HW4 = 96*96;
    int bid = blockIdx.x, tid = threadIdx.x;
    if (bid < 4608){
        int i = bid*256 + tid;
        M1[i] = (roi[i] > 0.8f) ? 1 : 0;
    } else if (bid < 5760){
        int i = (bid-4608)*256 + tid;
        int n = i / HW2, p = i - n*HW2;
        int oy = p / 192, ox = p - oy*192;
        const float* r = roi + (size_t)n*HW1;
        int v = 0;
        #pragma unroll
        for (int ky=0; ky<3; ky++){
            int iy = 2*oy + ky - 1;
            if ((unsigned)iy >= 384u) continue;
            #pragma unroll
            for (int kx=0; kx<3; kx++){
                int ix = 2*ox + kx - 1;
                if ((unsigned)ix < 384u) v |= (r[iy*384 + ix] > 0.8f);
            }
        }
        M2[i] = (u8)v;
    } else if (bid < 6048){
        int i = (bid-5760)*256 + tid;
        int n = i / HW4, p = i - n*HW4;
        int oy = p / 96, ox = p - oy*96;
        const float* r = roi + (size_t)n*HW1;
        int v = 0;
        for (int dy=-3; dy<=3; dy++){
            int iy = 4*oy + dy;
            if ((unsigned)iy >= 384u) continue;
            for (int dx=-3; dx<=3; dx++){
                int ix = 4*ox + dx;
                if ((unsigned)ix < 384u) v |= (r[iy*384 + ix] > 0.8f);
            }
        }
        M4[i] = (u8)v;
    } else if (bid < 6264){
        int local = bid - 6048;
        int a = local / 36;
        int j = (local - a*36)*256 + tid;
        const float* src = (a==0)? w1b : (a==1)? i2 : (a==2)? l5 : (a==3)? r1a : (a==4)? w2b : w2a;
        float sc = (a==2) ? 1.0f : BNS;
        if (j < 9216){
            int co = j/288, r = j%288, ci = r/9, k = r%9;
            WT[a*9216 + k*1024 + co*32 + ci] = f2bs(src[j]*sc);
        }
    } else if (bid < 6984){
        int local = bid - 6264;
        int a = local / 144;
        int j = (local - a*144)*256 + tid;
        if (a < 2){
            if (j < 36864){
                int co = j/576, r = j%576, ci = r/9, k = r%9;
                const float* s = a ? w4b : inv4;
                WT4[a*36864 + k*4096 + co*64 + ci] = f2bs(s[j]*BNS);
            }
        } else if (a < 4){
            if (j < 18432){
                int co = j/576, r = j%576, ci = r/9, k = r%9;
                const float* s = (a==2) ? l4s : r4w1;
                float sc = (a==2) ? 1.0f : BNS;
                WT4[73728 + (a-2)*18432 + k*2048 + co*64 + ci] = f2bs(s[j]*sc);
            }
        } else {
            if (j < 18432){
                int co = j/288, r = j%288, ci = r/9, k = r%9;
                WT4[110592 + k*2048 + co*32 + ci] = f2bs(w4a[j]*BNS);
            }
        }
    } else {
        int local = bid - 6984;
        int a = local / 18;
        int j = (local - a*18)*256 + tid;
        if (a == 0){
            if (j < 2048){
                int h = j >> 10, r = j & 1023, co = r >> 5, kq = r & 31;
                int q = h*32 + kq;
                d1a[j] = (q < 36) ? f2bs(w1a[co*36 + q]*BNS) : 0;
            }
        } else {
            if (j < 4608){
                int k = j/512, r = j%512, co = r/32, ci = r%32;
                const float* s = (a==1) ? r1w2 : r4w2;
                dh[(a-1)*4608 + j] = (co == 0) ? f2bs(s[ci*9 + k]) : 0;
            }
        }
    }
}

// ---------------- generic MFMA stride-1 conv; k-outer / site-inner ------------
template<int CIN, int COUT, int EPI, int TH>
__global__ __launch_bounds__(256) void mconv_s1(const short* __restrict__ in, int H,
                                                const short* __restrict__ wT,
                                                const u8* __restrict__ mask,
                                                const float* __restrict__ res32,
                                                short* __restrict__ out, int tilesX)
{
    const int HW = H*H;
    const int HV = CIN/32, G = COUT/16, CH8 = CIN/8;
    const int SR = TH + 2;
    const int SITES = SR*18;
    const int PS = (SITES | 1)*8;
    const int U2N = TH/4;
    int tY = blockIdx.x / tilesX, tX = blockIdx.x % tilesX, n = blockIdx.z;
    int y0 = tY*TH, x0 = tX*16;

    __shared__ __align__(16) short s_in[CH8*((SITES|1)*8)];
    __shared__ u8 s_m[TH*16];

    int tid = threadIdx.x;
    const short* inN = in + (size_t)n*HW*CIN;
    for (int i = tid; i < SITES*CH8; i += 256){
        int r = i/CH8, q = i%CH8;     // CH8 pow2 -> shifts
        int ry = r/18, rx = r%18;
        int gy = y0-1+ry, gx = x0-1+rx;
        bf16x8 v = {0,0,0,0,0,0,0,0};
        if ((unsigned)gy < (unsigned)H && (unsigned)gx < (unsigned)H)
            v = *(const bf16x8*)(inN + ((size_t)gy*H + gx)*CIN + q*8);
        *(bf16x8*)(s_in + q*PS + r*8) = v;
    }
    for (int i = tid; i < TH*16; i += 256){
        int ty = i>>4, tx = i&15;
        s_m[i] = mask[(size_t)n*HW + (y0+ty)*H + x0+tx];
    }
    __syncthreads();

    int wv = tid >> 6, lane = tid & 63;
    int nQ = lane >> 4, nn = lane & 15;

    f32x4 acc[U2N][G];
    #pragma unroll
    for (int u2=0; u2<U2N; ++u2)
        #pragma unroll
        for (int g=0; g<G; ++g) acc[u2][g] = (f32x4){0,0,0,0};

    #pragma unroll
    for (int h=0; h<HV; ++h){
        const short* bh[U2N];
        #pragma unroll
        for (int u2=0; u2<U2N; ++u2){
            int ty = u2*4 + wv;
            bh[u2] = s_in + (h*4+nQ)*PS + (ty*18 + nn)*8;
        }
        #pragma unroll
        for (int ky=0; ky<3; ++ky)
            #pragma unroll
            for (int kx=0; kx<3; ++kx){
                const int k = ky*3+kx;
                bf16x8 a[G];
                #pragma unroll
                for (int g=0; g<G; ++g)
                    a[g] = *(const bf16x8*)(wT + k*COUT*CIN + (g*16+nn)*CIN + h*32 + nQ*8);
                #pragma unroll
                for (int u2=0; u2<U2N; ++u2){
                    bf16x8 bfr = ld8(bh[u2] + (ky*18+kx)*8);
                    #pragma unroll
                    for (int g=0; g<G; ++g)
                        acc[u2][g] = MFMA_B16(a[g], bfr, acc[u2][g], 0,0,0);
                }
            }
    }

    #pragma unroll
    for (int u2=0; u2<U2N; ++u2){
        int nt = u2*4 + wv;
        int p = (y0+nt)*H + x0+nn;
        u8 m = s_m[nt*16 + nn];
        short* op = out + ((size_t)n*HW + p)*COUT;
        #pragma unroll
        for (int g=0; g<G; ++g){
            float r[4];
            #pragma unroll
            for (int e=0; e<4; ++e){
                int co = g*16 + nQ*4 + e;
                float a = acc[u2][g][e], o;
                if      (EPI == 0) o = m ? fmaxf(a,0.f) : 0.f;
                else if (EPI == 1) o = m ? lrelu(a) : 0.f;
                else o = m ? fmaxf(a,0.f) + res32[((size_t)(n>>2)*COUT + co)*(size_t)HW + p] : 0.f;
                r[e] = o;
            }
            bf16x4 w4 = {f2bs(r[0]),f2bs(r[1]),f2bs(r[2]),f2bs(r[3])};
            *(bf16x4*)(op + g*16 + nQ*4) = w4;
        }
    }
}

// ---------------- MFMA stride-2 conv: CIN=32; k-outer / site-inner ----------
template<int COUT, int THO>
__global__ __launch_bounds__(256) void mconv_s2m(const short* __restrict__ in, int IH,
                                                 const short* __restrict__ wT,   // [9][COUT][32]
                                                 const u8* __restrict__ mask,
                                                 short* __restrict__ out, int OH, int tilesX)
{
    const int IHW = IH*IH, OHW = OH*OH, G = COUT/16;
    const int IR = 2*THO + 1;
    const int SITES = IR*33;
    const int PS = (SITES|1)*8;
    const int ITN = THO/4;
    int tY = blockIdx.x / tilesX, tX = blockIdx.x % tilesX, n = blockIdx.z;
    int y0 = tY*THO, x0 = tX*16;

    __shared__ __align__(16) short s_in[4*((SITES|1)*8)];
    __shared__ u8 s_m[THO*16];

    int tid = threadIdx.x;
    const short* inN = in + (size_t)n*IHW*32;
    for (int i = tid; i < SITES*4; i += 256){
        int r = i>>2, q = i&3;
        int ry = r/33, rx = r%33;
        int gy = 2*y0-1+ry, gx = 2*x0-1+rx;
        bf16x8 v = {0,0,0,0,0,0,0,0};
        if ((unsigned)gy < (unsigned)IH && (unsigned)gx < (unsigned)IH)
            v = *(const bf16x8*)(inN + ((size_t)gy*IH + gx)*32 + q*8);
        *(bf16x8*)(s_in + q*PS + r*8) = v;
    }
    for (int i = tid; i < THO*16; i += 256){
        int ty = i>>4, tx = i&15;
        s_m[i] = mask[(size_t)n*OHW + (y0+ty)*OH + x0+tx];
    }
    __syncthreads();

    int wv = tid >> 6, lane = tid & 63;
    int nQ = lane >> 4, nn = lane & 15;

    f32x4 acc[ITN][G];
    #pragma unroll
    for (int it=0; it<ITN; ++it)
        #pragma unroll
        for (int g=0; g<G; ++g) acc[it][g] = (f32x4){0,0,0,0};

    const short* pb[ITN];
    #pragma unroll
    for (int it=0; it<ITN; ++it){
        int nt = it*4 + wv;
        pb[it] = s_in + nQ*PS + ((2*nt)*33 + 2*nn)*8;
    }

    #pragma unroll
    for (int ky=0; ky<3; ++ky)
        #pragma unroll
        for (int kx=0; kx<3; ++kx){
            const int k = ky*3+kx;
            bf16x8 a[G];
            #pragma unroll
            for (int g=0; g<G; ++g)
                a[g] = *(const bf16x8*)(wT + k*COUT*32 + (g*16+nn)*32 + nQ*8);
            #pragma unroll
            for (int it=0; it<ITN; ++it){
                bf16x8 bfr = ld8(pb[it] + (ky*33+kx)*8);
                #pragma unroll
                for (int g=0; g<G; ++g)
                    acc[it][g] = MFMA_B16(a[g], bfr, acc[it][g], 0,0,0);
            }
        }

    #pragma unroll
    for (int it=0; it<ITN; ++it){
        int nt = it*4 + wv;
        int p = (y0+nt)*OH + x0+nn;
        u8 m = s_m[nt*16 + nn];
        short* op = out + ((size_t)n*OHW + p)*COUT;
        #pragma unroll
        for (int g=0; g<G; ++g){
            float r[4];
            #pragma unroll
            for (int e=0; e<4; ++e) r[e] = m ? fmaxf(acc[it][g][e],0.f) : 0.f;
            bf16x4 w4 = {f2bs(r[0]),f2bs(r[1]),f2bs(r[2]),f2bs(r[3])};
            *(bf16x4*)(op + g*16 + nQ*4) = w4;
        }
    }
}

// ---------------- fused refine_OS4: t = lrelu(conv64->32(xs))*m4; out = conv32->1(t)+b ----
template<int TH>
__global__ __launch_bounds__(256) void mconv_ref4(const short* __restrict__ in, int H,
                                                  const short* __restrict__ wTa,   // [9][32co][64ci]
                                                  const short* __restrict__ wTh,   // [9][16][32]
                                                  const float* __restrict__ bias,
                                                  const u8* __restrict__ mask,
                                                  float* __restrict__ out, int tilesX)
{
    const int HW = H*H;
    const int XR = TH+4, XSITES = XR*20;
    const int PSX = (XSITES|1)*8;
    const int TR = TH+2, TSITES = TR*18;
    const int PST = (TSITES|1)*8;
    int tY = blockIdx.x / tilesX, tX = blockIdx.x % tilesX, n = blockIdx.z;
    int y0 = tY*TH, x0 = tX*16;

    __shared__ __align__(16) short s_xs[8*((XSITES|1)*8)];
    __shared__ __align__(16) short s_t[4*((TSITES|1)*8)];
    __shared__ u8 s_m[TSITES];

    int tid = threadIdx.x;
    const short* inN = in + (size_t)n*HW*64;
    for (int i = tid; i < XSITES*8; i += 256){
        int r = i>>3, q = i&7;
        int ry = r/20, rx = r%20;
        int gy = y0-2+ry, gx = x0-2+rx;
        bf16x8 v = {0,0,0,0,0,0,0,0};
        if ((unsigned)gy < (unsigned)H && (unsigned)gx < (unsigned)H)
            v = *(const bf16x8*)(inN + ((size_t)gy*H + gx)*64 + q*8);
        *(bf16x8*)(s_xs + q*PSX + r*8) = v;
    }
    for (int i = tid; i < TSITES; i += 256){
        int vy = i/18, vx = i%18;
        int gy = y0-1+vy, gx = x0-1+vx;
        s_m[i] = ((unsigned)gy < (unsigned)H && (unsigned)gx < (unsigned)H) ? mask[(size_t)n*HW + gy*H + gx] : 0;
    }
    __syncthreads();

    int wv = tid >> 6, lane = tid & 63;
    int nQ = lane >> 4, nn = lane & 15;

    // t-phase (dense; mask4 is near-full density)
    const int TG = (TSITES + 15)/16;
    for (int g8 = wv; g8 < TG; g8 += 4){
        int s0 = g8*16 + nn;
        int s = s0 >= TSITES ? TSITES-1 : s0;
        int vy = s/18, vx = s - vy*18;
        const short* pb = s_xs + nQ*PSX + (vy*20 + vx)*8;
        f32x4 acc0 = {0,0,0,0}, acc1 = {0,0,0,0};
        #pragma unroll
        for (int ky=0; ky<3; ++ky)
            #pragma unroll
            for (int kx=0; kx<3; ++kx){
                const int k = ky*3+kx;
                const short* wk = wTa + k*2048;
                bf16x8 xlo = ld8(pb + (ky*20+kx)*8);
                bf16x8 xhi = ld8(pb + 4*PSX + (ky*20+kx)*8);
                bf16x8 a0lo = *(const bf16x8*)(wk + nn*64 + nQ*8);
                bf16x8 a0hi = *(const bf16x8*)(wk + nn*64 + 32 + nQ*8);
                bf16x8 a1lo = *(const bf16x8*)(wk + (16+nn)*64 + nQ*8);
                bf16x8 a1hi = *(const bf16x8*)(wk + (16+nn)*64 + 32 + nQ*8);
                acc0 = MFMA_B16(a0lo, xlo, acc0, 0,0,0);
                acc0 = MFMA_B16(a0hi, xhi, acc0, 0,0,0);
                acc1 = MFMA_B16(a1lo, xlo, acc1, 0,0,0);
                acc1 = MFMA_B16(a1hi, xhi, acc1, 0,0,0);
            }
        if (s0 < TSITES){
            u8 m = s_m[s0];
            #pragma unroll
            for (int g=0; g<2; ++g){
                float r[4];
                #pragma unroll
                for (int e=0; e<4; ++e){
                    float a = g ? acc1[e] : acc0[e];
                    r[e] = m ? lrelu(a) : 0.f;
                }
                bf16x4 w4 = {f2bs(r[0]),f2bs(r[1]),f2bs(r[2]),f2bs(r[3])};
                *(bf16x4*)(s_t + (g*2 + (nQ>>1))*PST + s0*8 + (nQ&1)*4) = w4;
            }
        }
    }
    __syncthreads();

    // head
    float bb = bias[0];
    for (int nt = wv; nt < TH; nt += 4){
        const short* pt = s_t + nQ*PST + (nt*18 + nn)*8;
        f32x4 acc = {0,0,0,0};
        #pragma unroll
        for (int ky=0; ky<3; ++ky)
            #pragma unroll
            for (int kx=0; kx<3; ++kx){
                const int k = ky*3+kx;
                bf16x8 aw = *(const bf16x8*)(wTh + k*512 + nn*32 + nQ*8);
                bf16x8 bfr = ld8(pt + (ky*18+kx)*8);
                acc = MFMA_B16(aw, bfr, acc, 0,0,0);
            }
        if (nQ == 0){
            u8 m = s_m[(nt+1)*18 + nn+1];
            out[(size_t)n*HW + (size_t)(y0+nt)*H + (x0+nn)] = m ? acc[0] + bb : -99.f;
        }
    }
}

// ---------------- conv1ab v7: sparse compacted site lists (mask1 ~20% dense) ----
__global__ __launch_bounds__(256) void conv1ab3(const float* __restrict__ image,
                                                const float* __restrict__ masks,
                                                const u8*  __restrict__ M1,
                                                const short* __restrict__ wT1a,   // [2][32co][32K]
                                                const short* __restrict__ wT1b,   // [9][32co][32ci]
                                                short* __restrict__ fea1)         // [N][HW][32]
{
    const int H = 384; const int HW = H*H;
    const int PS = 181*8;
    int tY = blockIdx.x / 48, tX = blockIdx.x % 48, n = blockIdx.z;
    int y0 = tY*16, x0 = tX*8;

    __shared__ float s_inp[4][240];
    __shared__ u8    s_m[240];
    __shared__ int   s_cnt[2];
    __shared__ unsigned short s_lF[180];
    __shared__ unsigned short s_lO[128];
    __shared__ __align__(16) short s_ic[8*(181*8)];
    __shared__ __align__(16) short s_f[4*(181*8)];

    int tid = threadIdx.x;
    const bf16x8 Z8 = {0,0,0,0,0,0,0,0};
    if (tid < 2) s_cnt[tid] = 0;
    // zero s_f (separate buffer -> no overlay hazard)
    for (int i = tid; i < 4*181; i += 256)
        *(bf16x8*)(s_f + i*8) = Z8;
    for (int i = tid; i < 240; i += 256){
        int ly = i/12, lxx = i%12;
        int gy = y0-2+ly, gx = x0-2+lxx;
        bool inb = ((unsigned)gy < 384u) && ((unsigned)gx < 384u);
        u8 mv = inb ? M1[(size_t)n*HW + gy*H + gx] : 0;
        s_m[i] = mv;
        float mm = (float)mv;
        int p = gy*H + gx;
        #pragma unroll
        for (int c = 0; c < 4; ++c){
            float v = 0.f;
            if (inb) v = (c < 3) ? image[((size_t)(n>>2)*3 + c)*HW + p]
                                 : masks[(size_t)n*HW + p];
            s_inp[c][i] = v*mm;
        }
    }
    __syncthreads();

    // build active-site lists
    for (int i = tid; i < 180; i += 256){
        int fy = i/10, fx = i - fy*10;
        if (s_m[(fy+1)*12 + fx+1]){
            int idx = atomicAdd(&s_cnt[0], 1);
            s_lF[idx] = (unsigned short)i;
        }
    }
    for (int i = tid; i < 128; i += 256){
        int ty = i>>3, tx = i&7;
        if (s_m[(ty+2)*12 + tx+2]){
            int idx = atomicAdd(&s_cnt[1], 1);
            s_lO[idx] = (unsigned short)i;
        }
    }
    __syncthreads();

    int cntF = s_cnt[0], cntO = s_cnt[1];

    // im2col only at listed f-sites (q fixed per thread since 256 % 64 == 0)
    {
        int q = tid & 63;
        int ci = q/9, kk = q - ci*9, ky = kk/3, kx = kk - ky*3;
        bool qok = q < 36;
        for (int i = tid; i < cntF*64; i += 256){
            int site = s_lF[i >> 6];
            short v = 0;
            if (qok){
                int fy = site/10, fx = site - fy*10;
                v = f2bs(s_inp[ci][(fy+ky)*12 + fx+kx]);
            }
            s_ic[(q>>3)*PS + site*8 + (q&7)] = v;
        }
    }
    __syncthreads();

    int wv = tid >> 6, lane = tid & 63;
    int nQ = lane >> 4, nn = lane & 15;

    // f-stage over listed groups; write straight to s_f (zeros elsewhere)
    {
        bf16x8 fa0[2], fa1[2];
        #pragma unroll
        for (int h=0;h<2;++h){
            fa0[h] = *(const bf16x8*)(wT1a + h*1024 + nn*32 + nQ*8);
            fa1[h] = *(const bf16x8*)(wT1a + h*1024 + (16+nn)*32 + nQ*8);
        }
        for (int base = wv*16; base < cntF; base += 64){
            int slot = base + nn;
            bool on = slot < cntF;
            int site = s_lF[on ? slot : 0];
            f32x4 a0 = {0,0,0,0}, a1 = {0,0,0,0};
            #pragma unroll
            for (int h=0;h<2;++h){
                bf16x8 bfr = ld8(s_ic + (h*4+nQ)*PS + site*8);
                a0 = MFMA_B16(fa0[h], bfr, a0, 0,0,0);
                a1 = MFMA_B16(fa1[h], bfr, a1, 0,0,0);
            }
            if (on){
                #pragma unroll
                for (int g=0; g<2; ++g){
                    float r[4];
                    #pragma unroll
                    for (int e=0; e<4; ++e){
                        float a = g ? a1[e] : a0[e];
                        r[e] = fmaxf(a,0.f);
                    }
                    bf16x4 w4 = {f2bs(r[0]),f2bs(r[1]),f2bs(r[2]),f2bs(r[3])};
                    *(bf16x4*)(s_f + (g*2 + (nQ>>1))*PS + site*8 + (nQ&1)*4) = w4;
                }
            }
        }
    }
    __syncthreads();

    // conv1b over listed output groups (k-loop per group, weights from L1)
    {
        for (int base = wv*16; base < cntO; base += 64){
            int slot = base + nn;
            bool on = slot < cntO;
            int os = s_lO[on ? slot : 0];
            int ty = os >> 3, tx = os & 7;
            const short* pb = s_f + nQ*PS + (ty*10 + tx)*8;
            f32x4 acc0 = {0,0,0,0}, acc1 = {0,0,0,0};
            #pragma unroll
            for (int ky=0; ky<3; ++ky)
                #pragma unroll
                for (int kx=0; kx<3; ++kx){
                    const int k = ky*3+kx;
                    bf16x8 a0 = *(const bf16x8*)(wT1b + k*1024 + nn*32 + nQ*8);
                    bf16x8 a1 = *(const bf16x8*)(wT1b + k*1024 + (16+nn)*32 + nQ*8);
                    bf16x8 bfr = ld8(pb + (ky*10+kx)*8);
                    acc0 = MFMA_B16(a0, bfr, acc0, 0,0,0);
                    acc1 = MFMA_B16(a1, bfr, acc1, 0,0,0);
                }
            if (on){
                short* fp = fea1 + ((size_t)n*HW + (size_t)(y0+ty)*H + (x0+tx))*32;
                #pragma unroll
                for (int g=0; g<2; ++g){
                    float r[4];
                    #pragma unroll
                    for (int e=0; e<4; ++e){
                        float a = g ? acc1[e] : acc0[e];
                        r[e] = fmaxf(a,0.f);
                    }
                    bf16x4 w4 = {f2bs(r[0]),f2bs(r[1]),f2bs(r[2]),f2bs(r[3])};
                    *(bf16x4*)(fp + g*16 + nQ*4) = w4;
                }
            }
        }
        // zero inactive fea1 sites (needed by dense downstream consumers)
        for (int i = tid; i < 128*4; i += 256){
            int os = i >> 2, q = i & 3;
            int ty = os >> 3, tx = os & 7;
            if (!s_m[(ty+2)*12 + tx+2])
                *(bf16x8*)(fea1 + ((size_t)n*HW + (size_t)(y0+ty)*H + (x0+tx))*32 + q*8) = Z8;
        }
    }
}

// ---------------- MFMA layer4; stage-2 k-outer (16x16 tile) ----------------
__global__ __launch_bounds__(256) void fk_l4c(const short* __restrict__ xs,
                                              const short* __restrict__ fea2,
                                              const u8*  __restrict__ M2,
                                              const short* __restrict__ wTi4,
                                              const short* __restrict__ wTl4,
                                              short* __restrict__ u_out)
{
    const int H2 = 192, HW2 = H2*H2, H4 = 96, HW4 = H4*H4;
    const int PSX = 101*8, PSU = 325*8;
    int tY = blockIdx.x / 12, tX = blockIdx.x % 12, n = blockIdx.z;
    int y0 = tY*16, x0 = tX*16;
    int uy0 = (y0>>1) - 1, ux0 = (x0>>1) - 1;

    __shared__ __align__(16) short s_xs[8*(101*8)];
    __shared__ __align__(16) short s_ul[8*(325*8)];
    __shared__ u8 s_m[324];

    int tid = threadIdx.x;
    const short* xN = xs + (size_t)n*HW4*64;
    for (int i = tid; i < 100*8; i += 256){
        int r = i>>3, q = i&7;
        int ly = r/10, lxx = r%10;
        int gy = uy0+ly, gx = ux0+lxx;
        bf16x8 v = {0,0,0,0,0,0,0,0};
        if ((unsigned)gy < 96u && (unsigned)gx < 96u)
            v = *(const bf16x8*)(xN + ((size_t)gy*H4 + gx)*64 + q*8);
        *(bf16x8*)(s_xs + q*PSX + r*8) = v;
    }
    for (int i = tid; i < 324; i += 256){
        int ry = i/18, rx = i%18; int gy = y0-1+ry, gx = x0-1+rx;
        s_m[i] = ((unsigned)gy < 192u && (unsigned)gx < 192u) ? M2[(size_t)n*HW2 + gy*H2 + gx] : 0;
    }

    int wv = tid >> 6, lane = tid & 63;
    int nQ = lane >> 4, nn = lane & 15;

    bf16x4 pf2v[4][2];
    {
        const short* f2N = fea2 + (size_t)n*HW2*32;
        #pragma unroll
        for (int u2=0; u2<4; ++u2){
            int nt = u2*4 + wv;
            int p = (y0+nt)*H2 + x0+nn;
            const short* fp = f2N + (size_t)p*32;
            pf2v[u2][0] = *(const bf16x4*)(fp + nQ*4);
            pf2v[u2][1] = *(const bf16x4*)(fp + 16 + nQ*4);
        }
    }
    __syncthreads();

    for (int ui = wv; ui < 24; ui += 4){
        int cls = ui/6, nt = ui%6;
        int pY = cls >> 1, pX = cls & 1;
        int s0 = nt*16 + nn;
        int s = s0 > 80 ? 80 : s0;
        int jr = s/9, jc = s%9;
        int ry = 2*jr + pY, rx = 2*jc + pX;

        int tiy[4], tix[4], twk[4]; int tapN;
        if (pY == 0){
            if (pX == 0){
                tiy[0]=jr;   tix[0]=jc;   twk[0]=8;
                tiy[1]=jr;   tix[1]=jc+1; twk[1]=6;
                tiy[2]=jr+1; tix[2]=jc;   twk[2]=2;
                tiy[3]=jr+1; tix[3]=jc+1; twk[3]=0; tapN=4;
            } else {
                tiy[0]=jr;   tix[0]=jc+1; twk[0]=7;
                tiy[1]=jr+1; tix[1]=jc+1; twk[1]=1; tapN=2;
            }
        } else {
            if (pX == 0){
                tiy[0]=jr+1; tix[0]=jc;   twk[0]=5;
                tiy[1]=jr+1; tix[1]=jc+1; twk[1]=3; tapN=2;
            } else {
                tiy[0]=jr+1; tix[0]=jc+1; twk[0]=4; tapN=1;
            }
        }

        f32x4 acc[4];
        #pragma unroll
        for (int g=0; g<4; ++g) acc[g] = (f32x4){0,0,0,0};
        for (int t = 0; t < tapN; ++t){
            int off = (tiy[t]*10 + tix[t])*8;
            bf16x8 xlo = ld8(s_xs + nQ*PSX + off);
            bf16x8 xhi = ld8(s_xs + (4+nQ)*PSX + off);
            const short* wk = wTi4 + twk[t]*4096;
            #pragma unroll
            for (int g=0; g<4; ++g){
                bf16x8 alo = *(const bf16x8*)(wk + (g*16+nn)*64 + nQ*8);
                bf16x8 ahi = *(const bf16x8*)(wk + (g*16+nn)*64 + 32 + nQ*8);
                acc[g] = MFMA_B16(alo, xlo, acc[g], 0,0,0);
                acc[g] = MFMA_B16(ahi, xhi, acc[g], 0,0,0);
            }
        }
        if (s0 <= 80){
            int sidx = ry*18 + rx;
            u8 m = s_m[sidx];
            #pragma unroll
            for (int g=0; g<4; ++g){
                float r[4];
                #pragma unroll
                for (int e=0; e<4; ++e){
                    float a = acc[g][e];
                    r[e] = m ? lrelu(a) : 0.f;
                }
                bf16x4 w4 = {f2bs(r[0]),f2bs(r[1]),f2bs(r[2]),f2bs(r[3])};
                *(bf16x4*)(s_ul + ((g>>1)*4 + (g&1)*2 + (nQ>>1))*PSU + sidx*8 + (nQ&1)*4) = w4;
            }
        }
    }
    __syncthreads();

    {
        f32x4 acc0[4], acc1[4];
        const short* pv[4];
        #pragma unroll
        for (int u2=0; u2<4; ++u2){
            acc0[u2] = (f32x4){0,0,0,0}; acc1[u2] = (f32x4){0,0,0,0};
            int nt = u2*4 + wv;
            pv[u2] = s_ul + nQ*PSU + (nt*18 + nn)*8;
        }
        #pragma unroll
        for (int ky=0; ky<3; ++ky)
            #pragma unroll
            for (int kx=0; kx<3; ++kx){
                int k = ky*3+kx;
                const short* wk = wTl4 + k*2048;
                bf16x8 a0lo = *(const bf16x8*)(wk + nn*64 + nQ*8);
                bf16x8 a0hi = *(const bf16x8*)(wk + nn*64 + 32 + nQ*8);
                bf16x8 a1lo = *(const bf16x8*)(wk + (16+nn)*64 + nQ*8);
                bf16x8 a1hi = *(const bf16x8*)(wk + (16+nn)*64 + 32 + nQ*8);
                #pragma unroll
                for (int u2=0; u2<4; ++u2){
                    bf16x8 vlo = ld8(pv[u2] + (ky*18+kx)*8);
                    bf16x8 vhi = ld8(pv[u2] + 4*PSU + (ky*18+kx)*8);
                    acc0[u2] = MFMA_B16(a0lo, vlo, acc0[u2], 0,0,0);
                    acc0[u2] = MFMA_B16(a0hi, vhi, acc0[u2], 0,0,0);
                    acc1[u2] = MFMA_B16(a1lo, vlo, acc1[u2], 0,0,0);
                    acc1[u2] = MFMA_B16(a1hi, vhi, acc1[u2], 0,0,0);
                }
            }
        #pragma unroll
        for (int u2 = 0; u2 < 4; ++u2){
            int nt = u2*4 + wv;
            int p = (y0+nt)*H2 + x0+nn;
            u8 m = s_m[(nt+1)*18 + nn+1];
            short* up = u_out + ((size_t)n*HW2 + p)*32;
            #pragma unroll
            for (int g=0; g<2; ++g){
                float r[4];
                #pragma unroll
                for (int e=0; e<4; ++e){
                    float a = g ? acc1[u2][e] : acc0[u2][e];
                    r[e] = m ? a + s2f(pf2v[u2][g][e]) : 0.f;
                }
                bf16x4 w4 = {f2bs(r[0]),f2bs(r[1]),f2bs(r[2]),f2bs(r[3])};
                *(bf16x4*)(up + g*16 + nQ*4) = w4;
            }
        }
    }
}

// ---------------- MFMA back end v14: sparse lists + T14 fea1 prefetch ----------------
__global__ __launch_bounds__(256) void fk_back8(const short* __restrict__ u,
                                                const short* __restrict__ fea1,   // [N][HW1][32]
                                                const u8*  __restrict__ M1,
                                                const short* __restrict__ wTi2,
                                                const short* __restrict__ wTl5,
                                                const short* __restrict__ wTr1a,
                                                const short* __restrict__ wTr1b,  // [9][16][32]
                                                const float* __restrict__ r1_b2,
                                                float* __restrict__ out1)
{
    const int H1 = 384, HW1 = H1*H1, H2 = 192, HW2 = H2*H2;
    const int PS_U = 97*8, PS_A = 309*8, PS_B = 241*8, PS_C = 181*8;
    int tY = blockIdx.x / 48, tX = blockIdx.x % 48, n = blockIdx.z;
    int y0 = tY*16, x0 = tX*8;
    int uy0 = (y0>>1) - 2, ux0 = (x0>>1) - 2;

    __shared__ __align__(16) short sP0[4*(309*8)];   // s_vl, then s_t1
    __shared__ __align__(16) short sP1[4*(241*8)];   // s_u, then s_v
    __shared__ u8 s_m[308];
    __shared__ int s_cnt[7];                          // A0..A3, B, C, D
    __shared__ unsigned s_lA[4*80];
    __shared__ unsigned s_lB[240];
    __shared__ unsigned s_lC[180];
    __shared__ unsigned s_lD[128];
    short* s_u  = sP1;
    short* s_vl = sP0;
    short* s_v  = sP1;
    short* s_t1 = sP0;

    int tid = threadIdx.x;
    const bf16x8 Z8 = {0,0,0,0,0,0,0,0};

    // ---- prologue: stage u, masks; zero vl; init counters ----
    if (tid < 7) s_cnt[tid] = 0;
    const short* uN = u + (size_t)n*HW2*32;
    for (int i = tid; i < 96*4; i += 256){
        int r = i>>2, q = i&3;
        int ly = r >> 3, lxx = r & 7;
        int gy = uy0+ly, gx = ux0+lxx;
        bf16x8 v = Z8;
        if ((unsigned)gy < 192u && (unsigned)gx < 192u)
            v = *(const bf16x8*)(uN + ((size_t)gy*H2 + gx)*32 + q*8);
        *(bf16x8*)(s_u + q*PS_U + r*8) = v;
    }
    for (int i = tid; i < 308; i += 256){
        int ry = i/14, rx = i%14; int gy = y0-3+ry, gx = x0-3+rx;
        s_m[i] = ((unsigned)gy < 384u && (unsigned)gx < 384u) ? M1[(size_t)n*HW1 + gy*H1 + gx] : 0;
    }
    for (int i = tid; i < 4*309; i += 256)
        *(bf16x8*)(s_vl + i*8) = Z8;
    __syncthreads();

    // ---- build compacted active-site lists ----
    for (int i = tid; i < 308; i += 256){
        if (s_m[i]){
            int ry = i/14, rx = i - ry*14;
            int cls = ((ry&1)<<1) | (rx&1);
            int jr = ry>>1, jc = rx>>1;
            int idx = atomicAdd(&s_cnt[cls], 1);
            s_lA[cls*80 + idx] = ((unsigned)i<<16) | (unsigned)(jr*8+jc);
        }
    }
    for (int i = tid; i < 240; i += 256){
        int vy = i/12, vx = i - vy*12;
        if (s_m[(vy+1)*14 + vx+1]){
            int idx = atomicAdd(&s_cnt[4], 1);
            s_lB[idx] = ((unsigned)i<<16) | (unsigned)(vy*14+vx);
        }
    }
    for (int i = tid; i < 180; i += 256){
        int qy = i/10, qx = i - qy*10;
        if (s_m[(qy+2)*14 + qx+2]){
            int idx = atomicAdd(&s_cnt[5], 1);
            s_lC[idx] = ((unsigned)i<<16) | (unsigned)(qy*12+qx);
        }
    }
    for (int i = tid; i < 128; i += 256){
        int ty = i>>3, tx = i&7;
        if (s_m[(ty+3)*14 + tx+3]){
            int idx = atomicAdd(&s_cnt[6], 1);
            s_lD[idx] = ((unsigned)i<<16) | (unsigned)(ty*10+tx);
        } else {
            out1[(size_t)n*HW1 + (size_t)(y0+ty)*H1 + (x0+tx)] = -99.f;
        }
    }
    __syncthreads();

    int wv = tid >> 6, lane = tid & 63;
    int nQ = lane >> 4, nn = lane & 15;

    // ---- T14 prefetch: issue stage-B fea1 residual loads now ----
    int cntB = s_cnt[4];
    bf16x4 pfB[4][2];
    #pragma unroll
    for (int it=0; it<4; ++it){
        int slot = wv*16 + it*64 + nn;
        if (slot < cntB){
            unsigned e = s_lB[slot];
            int wr = e >> 16;
            int vy = wr/12, vx = wr - vy*12;
            const short* f1 = fea1 + ((size_t)n*HW1 + (size_t)(y0-2+vy)*H1 + (x0-2+vx))*32;
            pfB[it][0] = *(const bf16x4*)(f1 + nQ*4);
            pfB[it][1] = *(const bf16x4*)(f1 + 16 + nQ*4);
        }
    }

    // ---- stage A (inv2): wave wv handles parity class wv ----
    {
        const int tN_[4]   = {4,2,2,1};
        const int tOff[4][4] = {{0,1,8,9},{1,9,9,9},{8,9,9,9},{9,9,9,9}};
        const int tWk [4][4] = {{8,6,2,0},{7,1,1,1},{5,3,3,3},{4,4,4,4}};
        int cnt = s_cnt[wv];
        int tn = tN_[wv];
        for (int base = 0; base < cnt; base += 16){
            int slot = base + nn;
            bool on = slot < cnt;
            unsigned e = s_lA[wv*80 + (on ? slot : 0)];
            int rb = e & 0xffff;
            f32x4 acc0 = {0,0,0,0}, acc1 = {0,0,0,0};
            for (int t = 0; t < tn; ++t){
                bf16x8 bfr = ld8(s_u + nQ*PS_U + (rb + tOff[wv][t])*8);
                const short* wp = wTi2 + tWk[wv][t]*1024;
                bf16x8 a0 = *(const bf16x8*)(wp + nn*32 + nQ*8);
                bf16x8 a1 = *(const bf16x8*)(wp + (16+nn)*32 + nQ*8);
                acc0 = MFMA_B16(a0, bfr, acc0, 0,0,0);
                acc1 = MFMA_B16(a1, bfr, acc1, 0,0,0);
            }
            if (on){
                int sidx = e >> 16;
                float r[8];
                #pragma unroll
                for (int g=0; g<2; ++g)
                    #pragma unroll
                    for (int ee=0; ee<4; ++ee)
                        r[g*4+ee] = lrelu(g ? acc1[ee] : acc0[ee]);
                bf16x4 w0 = {f2bs(r[0]),f2bs(r[1]),f2bs(r[2]),f2bs(r[3])};
                bf16x4 w1 = {f2bs(r[4]),f2bs(r[5]),f2bs(r[6]),f2bs(r[7])};
                *(bf16x4*)(s_vl + (nQ>>1)*PS_A     + sidx*8 + (nQ&1)*4) = w0;
                *(bf16x4*)(s_vl + (2+(nQ>>1))*PS_A + sidx*8 + (nQ&1)*4) = w1;
            }
        }
    }
    __syncthreads();

    // ---- zero v (overlays u; u now dead) ----
    for (int i = tid; i < 4*241; i += 256)
        *(bf16x8*)(s_v + i*8) = Z8;
    __syncthreads();

    // ---- stage B (l5 + fea1 residual from prefetched regs), compacted ----
    {
        #pragma unroll
        for (int it=0; it<4; ++it){
            int base = wv*16 + it*64;
            if (base < cntB){
                int slot = base + nn;
                bool on = slot < cntB;
                unsigned e = s_lB[on ? slot : 0];
                int rb = e & 0xffff;
                int wr = e >> 16;
                const short* pv = s_vl + nQ*PS_A + rb*8;
                f32x4 acc0 = {0,0,0,0}, acc1 = {0,0,0,0};
                #pragma unroll
                for (int ky=0; ky<3; ++ky)
                    #pragma unroll
                    for (int kx=0; kx<3; ++kx){
                        const int k = ky*3+kx;
                        bf16x8 wb0 = *(const bf16x8*)(wTl5 + k*1024 + nn*32 + nQ*8);
                        bf16x8 wb1 = *(const bf16x8*)(wTl5 + k*1024 + (16+nn)*32 + nQ*8);
                        bf16x8 bfr = ld8(pv + (ky*14+kx)*8);
                        acc0 = MFMA_B16(wb0, bfr, acc0, 0,0,0);
                        acc1 = MFMA_B16(wb1, bfr, acc1, 0,0,0);
                    }
                if (on){
                    float r[8];
                    #pragma unroll
                    for (int ee=0; ee<4; ++ee){
                        r[ee]   = acc0[ee] + s2f(pfB[it][0][ee]);
                        r[4+ee] = acc1[ee] + s2f(pfB[it][1][ee]);
                    }
                    bf16x4 w0 = {f2bs(r[0]),f2bs(r[1]),f2bs(r[2]),f2bs(r[3])};
                    bf16x4 w1 = {f2bs(r[4]),f2bs(r[5]),f2bs(r[6]),f2bs(r[7])};
                    *(bf16x4*)(s_v + (nQ>>1)*PS_B     + wr*8 + (nQ&1)*4) = w0;
                    *(bf16x4*)(s_v + (2+(nQ>>1))*PS_B + wr*8 + (nQ&1)*4) = w1;
                }
            }
        }
    }
    __syncthreads();

    // ---- zero t1 (overlays vl; vl now dead) ----
    for (int i = tid; i < 4*181; i += 256)
        *(bf16x8*)(s_t1 + i*8) = Z8;
    __syncthreads();

    // ---- stage C (r1a), compacted ----
    {
        int cnt = s_cnt[5];
        for (int base = wv*16; base < cnt; base += 64){
            int slot = base + nn;
            bool on = slot < cnt;
            unsigned e = s_lC[on ? slot : 0];
            int rb = e & 0xffff;
            const short* pv = s_v + nQ*PS_B + rb*8;
            f32x4 acc0 = {0,0,0,0}, acc1 = {0,0,0,0};
            #pragma unroll
            for (int ky=0; ky<3; ++ky)
                #pragma unroll
                for (int kx=0; kx<3; ++kx){
                    const int k = ky*3+kx;
                    bf16x8 wc0 = *(const bf16x8*)(wTr1a + k*1024 + nn*32 + nQ*8);
                    bf16x8 wc1 = *(const bf16x8*)(wTr1a + k*1024 + (16+nn)*32 + nQ*8);
                    bf16x8 bfr = ld8(pv + (ky*12+kx)*8);
                    acc0 = MFMA_B16(wc0, bfr, acc0, 0,0,0);
                    acc1 = MFMA_B16(wc1, bfr, acc1, 0,0,0);
                }
            if (on){
                int wr = e >> 16;
                float r[8];
                #pragma unroll
                for (int g=0; g<2; ++g)
                    #pragma unroll
                    for (int ee=0; ee<4; ++ee)
                        r[g*4+ee] = lrelu(g ? acc1[ee] : acc0[ee]);
                bf16x4 w0 = {f2bs(r[0]),f2bs(r[1]),f2bs(r[2]),f2bs(r[3])};
                bf16x4 w1 = {f2bs(r[4]),f2bs(r[5]),f2bs(r[6]),f2bs(r[7])};
                *(bf16x4*)(s_t1 + (nQ>>1)*PS_C     + wr*8 + (nQ&1)*4) = w0;
                *(bf16x4*)(s_t1 + (2+(nQ>>1))*PS_C + wr*8 + (nQ&1)*4) = w1;
            }
        }
    }
    __syncthreads();

    // ---- stage D (r1b head), compacted; inactive already written -99 ----
    {
        float bb = r1_b2[0];
        int cnt = s_cnt[6];
        for (int base = wv*16; base < cnt; base += 64){
            int slot = base + nn;
            bool on = slot < cnt;
            unsigned e = s_lD[on ? slot : 0];
            int rb = e & 0xffff;
            const short* pt = s_t1 + nQ*PS_C + rb*8;
            f32x4 acc = {0,0,0,0};
            #pragma unroll
            for (int ky=0; ky<3; ++ky)
                #pragma unroll
                for (int kx=0; kx<3; ++kx){
                    const int k = ky*3+kx;
                    bf16x8 aw = *(const bf16x8*)(wTr1b + k*512 + nn*32 + nQ*8);
                    bf16x8 bfr = ld8(pt + (ky*10+kx)*8);
                    acc = MFMA_B16(aw, bfr, acc, 0,0,0);
                }
            if (on && nQ == 0){
                int wr = e >> 16;
                int ty = wr >> 3, tx = wr & 7;
                out1[(size_t)n*HW1 + (size_t)(y0+ty)*H1 + (x0+tx)] = acc[0] + bb;
            }
        }
    }
}

// ---------------- launch ----------------

extern "C" void kernel_launch(void* const* d_in, const int* in_sizes, int n_in,
                              void* d_out, int out_size, void* d_ws, size_t ws_size,
                              hipStream_t stream)
{
    const float* x      = (const float*)d_in[0];
    const float* image  = (const float*)d_in[1];
    const float* masks  = (const float*)d_in[2];
    const float* roi    = (const float*)d_in[3];
    const float* w1a    = (const float*)d_in[4];
    const float* w1b    = (const float*)d_in[5];
    const float* w2a    = (const float*)d_in[6];
    const float* w2b    = (const float*)d_in[7];
    const float* w4a    = (const float*)d_in[8];
    const float* w4b    = (const float*)d_in[9];
    const float* inv4_w = (const float*)d_in[10];
    const float* l4_sub = (const float*)d_in[11];
    const float* inv2_w = (const float*)d_in[12];
    const float* l5_sub = (const float*)d_in[13];
    const float* r4_w1  = (const float*)d_in[14];
    const float* r4_w2  = (const float*)d_in[15];
    const float* r4_b2  = (const float*)d_in[16];
    const float* r1_w1  = (const float*)d_in[17];
    const float* r1_w2  = (const float*)d_in[18];
    const float* r1_b2  = (const float*)d_in[19];
    float* out = (float*)d_out;

    const int N = 8;
    const int H1 = 384, HW1 = 384*384;
    const int H2 = 192, HW2 = 192*192;
    const int H4 = 96,  HW4 = 96*96;

    char* wsp = (char*)d_ws;
    size_t off = 0;
    auto alloc = [&](size_t bytes) -> char* {
        char* p = wsp + off;
        off += (bytes + 255) & ~(size_t)255;
        return p;
    };
    bf16* FEA1 = (bf16*)alloc((size_t)N*32*HW1*2);  // interleaved [N][HW1][32]
    u8*   M1   = (u8*)alloc((size_t)N*HW1);
    u8*   M2   = (u8*)alloc((size_t)N*HW2);
    u8*   M4   = (u8*)alloc((size_t)N*HW4);
    bf16* FEA2 = (bf16*)alloc((size_t)N*32*HW2*2);  // interleaved [N][HW2][32]
    bf16* XS   = (bf16*)alloc((size_t)N*64*HW4*2);  // interleaved [N][HW4][64]
    bf16* GU   = (bf16*)alloc((size_t)N*32*HW2*2);  // interleaved (g then u)
    bf16* HT   = (bf16*)alloc((size_t)N*64*HW4*2);  // interleaved (h 64ch)
    short* WT   = (short*)alloc(6*9216*2);
    short* WT4  = (short*)alloc((size_t)129024*2);
    short* WT1a = (short*)alloc(2048*2);
    short* WTh  = (short*)alloc(2*4608*2);
    (void)ws_size; (void)in_sizes; (void)n_in; (void)out_size;

    short* wT1b  = WT;
    short* wTi2  = WT + 9216;
    short* wTl5  = WT + 2*9216;
    short* wTr1a = WT + 3*9216;
    short* wT2b  = WT + 4*9216;
    short* wT2a  = WT + 5*9216;
    short* wTi4  = WT4;
    short* wT4b  = WT4 + 36864;
    short* wTl4  = WT4 + 73728;
    short* wTr4a = WT4 + 92160;
    short* wT4a  = WT4 + 110592;
    short* wTr1b = WTh;
    short* wTr4b = WTh + 4608;

    dim3 blk(256);

    // fused prep: all masks + all weight transforms in one dispatch
    k_prep<<<dim3(7038), blk, 0, stream>>>(roi, w1b, inv2_w, l5_sub, r1_w1, w2b, w2a,
                                           inv4_w, w4b, l4_sub, r4_w1, w4a,
                                           w1a, r1_w2, r4_w2,
                                           M1, M2, M4, WT, WT4, WT1a, WTh);

    // front
    conv1ab3<<<dim3(1152, 1, N), blk, 0, stream>>>(image, masks, M1, WT1a, wT1b, (short*)FEA1);
    mconv_s2m<32,8><<<dim3(288, 1, N), blk, 0, stream>>>((const short*)FEA1, H1, wT2a, M2, (short*)GU, H2, 12);
    mconv_s1<32,32,0,8><<<dim3(288, 1, N), blk, 0, stream>>>((const short*)GU, H2, wT2b, M2, nullptr, (short*)FEA2, 12);
    mconv_s2m<64,4><<<dim3(144, 1, N), blk, 0, stream>>>((const short*)FEA2, H2, wT4a, M4, (short*)HT, H4, 6);
    mconv_s1<64,64,3,4><<<dim3(144, 1, N), blk, 0, stream>>>((const short*)HT, H4, wT4b, M4, x, (short*)XS, 6);

    // refine_OS4 fused (t + head in one kernel)
    mconv_ref4<4><<<dim3(144, 1, N), blk, 0, stream>>>((const short*)XS, H4, wTr4a, wTr4b, r4_b2, M4, out, 6);

    // layer4 fused (MFMA) -> u  (16x16 tile)
    fk_l4c<<<dim3(144, 1, N), blk, 0, stream>>>((const short*)XS, (const short*)FEA2, M2,
                                                wTi4, wTl4, (short*)GU);

    // MFMA back end -> out1
    fk_back8<<<dim3(1152, 1, N), blk, 0, stream>>>((const short*)GU, (const short*)FEA1, M1,
                                                   wTi2, wTl5, wTr1a, wTr1b, r1_b2,
                                                   out + (size_t)N*HW4);
}